// Round 13
// baseline (292.560 us; speedup 1.0000x reference)
//
#include <hip/hip_runtime.h>
#include <hip/hip_bf16.h>
#include <stdint.h>
#include <stddef.h>

#define S_LEN 2048
#define HID   3584
#define NH    28
#define NKV   4
#define HD    128
#define REP   7
#define KVD   512
#define NQKV  4608          // 3584 + 512 + 512
#define KSPLIT_LEN 1792     // 3584 / 2 (oproj + fallback qkv)
// QK scale with log2(e) folded in: softmax uses exp2
#define QK_SCALE_L2E 0.12752462155f   // (1/sqrt(128)) * log2(e)

typedef unsigned short u16;
typedef short short8 __attribute__((ext_vector_type(8)));
typedef float f32x4 __attribute__((ext_vector_type(4)));

__device__ __forceinline__ u16 f2bf(float f) {
  union { float f; uint32_t u; } v; v.f = f;
  uint32_t r = v.u + 0x7fffu + ((v.u >> 16) & 1u);
  return (u16)(r >> 16);
}
__device__ __forceinline__ float bf2f(u16 u) {
  union { uint32_t u; float f; } v; v.u = ((uint32_t)u) << 16;
  return v.f;
}
__device__ __forceinline__ u16 nbf(float f) {  // native 1-op RNE cvt
  __hip_bfloat16 h = __float2bfloat16(f);
  return *reinterpret_cast<u16*>(&h);
}

#define GLL16(gp, lp) __builtin_amdgcn_global_load_lds( \
    (const __attribute__((address_space(1))) void*)(gp), \
    (__attribute__((address_space(3))) void*)(lp), 16, 0, 0)

// ---------------- f32 -> bf16 bulk convert (all 5 buffers, one launch) -------
__global__ __launch_bounds__(256) void cvt_all_kernel(
    const float* __restrict__ h, const float* __restrict__ qw,
    const float* __restrict__ kw, const float* __restrict__ vw,
    const float* __restrict__ ow,
    u16* __restrict__ hb, u16* __restrict__ qwb, u16* __restrict__ kwb,
    u16* __restrict__ vwb, u16* __restrict__ owb)
{
  const float* src; u16* dst; int n4;
  switch (blockIdx.y) {
    case 0: src = h;  dst = hb;  n4 = S_LEN * HID / 4; break;
    case 1: src = qw; dst = qwb; n4 = HID * HID / 4;   break;
    case 2: src = kw; dst = kwb; n4 = KVD * HID / 4;   break;
    case 3: src = vw; dst = vwb; n4 = KVD * HID / 4;   break;
    default: src = ow; dst = owb; n4 = HID * HID / 4;  break;
  }
  int i = blockIdx.x * blockDim.x + threadIdx.x;
  const int stride = gridDim.x * blockDim.x;
  for (; i < n4; i += stride) {
    float4 v = reinterpret_cast<const float4*>(src)[i];
    uint2 o;
    o.x = (uint32_t)f2bf(v.x) | ((uint32_t)f2bf(v.y) << 16);
    o.y = (uint32_t)f2bf(v.z) | ((uint32_t)f2bf(v.w) << 16);
    reinterpret_cast<uint2*>(dst)[i] = o;
  }
}

// ---- GEMM core: 128x256 tile, 8 waves (2Mx4N, wave=64x64), BK=32,
// triple-buffered LDS (24KB/buf -> 72KB total -> 2 blocks/CU), counted
// vmcnt (3 loads/thread/tile in flight; vmcnt(0) only at tail).
__device__ __forceinline__ void gemm_core_128x256_bk32(
    u16* lds, const u16* __restrict__ A, const u16* __restrict__ W,
    u16* __restrict__ C, int ldC, int lda, int T)
{
  const int t  = threadIdx.x;       // 0..511
  const int l  = t & 63;
  const int w  = t >> 6;            // 0..7
  const int lr = l & 15;
  const int lg = l >> 4;
  const int wm = (w >> 2) << 6;     // 0 or 64
  const int wn = (w & 3) << 6;      // 0,64,128,192
  const int sw = (((lr & 3) ^ ((lr >> 2) & 3)) << 3);

  const f32x4 fz = {0.f, 0.f, 0.f, 0.f};
  f32x4 acc[4][4];
#pragma unroll
  for (int i = 0; i < 4; ++i)
#pragma unroll
    for (int j = 0; j < 4; ++j) acc[i][j] = fz;

#define SWZC(e) ((e & 31) ^ ((((e >> 5) & 3) ^ ((e >> 7) & 3)) << 3))
#define STAGE3(kt, buf) do {                                          \
    { const int e_ = t * 8;                                           \
      const int r_ = e_ >> 5;  const int c_ = SWZC(e_);               \
      GLL16(A + (size_t)(kt) * 32 + (size_t)r_ * lda + c_, (buf) + e_); } \
    _Pragma("unroll")                                                 \
    for (int i_ = 0; i_ < 2; ++i_) {                                  \
      const int e_ = (i_ * 512 + t) * 8;                              \
      const int r_ = e_ >> 5;  const int c_ = SWZC(e_);               \
      GLL16(W + (size_t)(kt) * 32 + (size_t)r_ * lda + c_, (buf) + 4096 + e_); } \
  } while (0)

  STAGE3(0, lds);
  STAGE3(1, lds + 12288);

#pragma unroll 1
  for (int tk = 0; tk < T; ++tk) {
    if (tk + 1 < T) { asm volatile("s_waitcnt vmcnt(3)" ::: "memory"); }
    else            { asm volatile("s_waitcnt vmcnt(0)" ::: "memory"); }
    __builtin_amdgcn_sched_barrier(0);
    __builtin_amdgcn_s_barrier();
    __builtin_amdgcn_sched_barrier(0);

    if (tk + 2 < T) {
      u16* nb = lds + ((tk + 2) % 3) * 12288;
      STAGE3(tk + 2, nb);
    }

    const u16* As_ = lds + (tk % 3) * 12288;
    const u16* Bs_ = As_ + 4096;
    short8 af[4], bfr[4];
#pragma unroll
    for (int mi = 0; mi < 4; ++mi)
      af[mi] = *(const short8*)(As_ + (wm + mi * 16 + lr) * 32 + ((lg * 8) ^ sw));
#pragma unroll
    for (int ni = 0; ni < 4; ++ni)
      bfr[ni] = *(const short8*)(Bs_ + (wn + ni * 16 + lr) * 32 + ((lg * 8) ^ sw));
    __builtin_amdgcn_s_setprio(1);
#pragma unroll
    for (int mi = 0; mi < 4; ++mi)
#pragma unroll
      for (int ni = 0; ni < 4; ++ni)
        acc[mi][ni] = __builtin_amdgcn_mfma_f32_16x16x32_bf16(af[mi], bfr[ni], acc[mi][ni], 0, 0, 0);
    __builtin_amdgcn_s_setprio(0);
  }
#undef STAGE3
#undef SWZC

#pragma unroll
  for (int ni = 0; ni < 4; ++ni) {
    const int n = wn + ni * 16 + lr;
#pragma unroll
    for (int mi = 0; mi < 4; ++mi) {
#pragma unroll
      for (int r = 0; r < 4; ++r) {
        const int m = wm + mi * 16 + lg * 4 + r;
        C[(size_t)m * ldC + n] = f2bf(acc[mi][ni][r]);
      }
    }
  }
}

// QKV: partials [Z][S][NQKV]; grid (16, 18, Z); XCD-chunk swizzle (288=8*36).
// Z (gridDim.z) = 4 when ws allows (tail-quantization fix), else 2.
__global__ __launch_bounds__(512) void qkv_gemm_kernel(
    const u16* __restrict__ hb,
    const u16* __restrict__ qwb, const u16* __restrict__ kwb, const u16* __restrict__ vwb,
    u16* __restrict__ part)
{
  __shared__ u16 lds[3 * 12288];
  const int lin = blockIdx.y * 16 + blockIdx.x;   // 0..287, dispatch-linear
  const int swz = (lin & 7) * 36 + (lin >> 3);    // bijective XCD chunking
  const int m0  = (swz & 15) * 128;
  const int by  = swz >> 4;                       // 0..17
  const int ksl = HID / gridDim.z;
  const int k0  = blockIdx.z * ksl;
  u16* Cz = part + (size_t)blockIdx.z * S_LEN * NQKV;
  const u16* Wp; size_t coff; int n0;
  if (by < 14)      { Wp = qwb; n0 = by * 256;        coff = n0; }
  else if (by < 16) { Wp = kwb; n0 = (by - 14) * 256; coff = HID + n0; }
  else              { Wp = vwb; n0 = (by - 16) * 256; coff = HID + KVD + n0; }
  gemm_core_128x256_bk32(lds, hb + (size_t)m0 * HID + k0,
                         Wp + (size_t)n0 * HID + k0,
                         Cz + (size_t)m0 * NQKV + coff, NQKV, HID, ksl / 32);
}

// O-proj: partials [2][S][HID]; grid (16, 14, 2); XCD swizzle (224=8*28)
__global__ __launch_bounds__(512) void oproj_gemm_kernel(
    const u16* __restrict__ ao, const u16* __restrict__ owb, u16* __restrict__ part)
{
  __shared__ u16 lds[3 * 12288];
  const int lin = blockIdx.y * 16 + blockIdx.x;   // 0..223
  const int swz = (lin & 7) * 28 + (lin >> 3);
  const int m0  = (swz & 15) * 128;
  const int n0  = (swz >> 4) * 256;
  const int k0  = blockIdx.z * KSPLIT_LEN;
  u16* Cz = part + (size_t)blockIdx.z * S_LEN * HID;
  gemm_core_128x256_bk32(lds, ao + (size_t)m0 * HID + k0,
                         owb + (size_t)n0 * HID + k0,
                         Cz + (size_t)m0 * HID + n0, HID, HID, KSPLIT_LEN / 32);
}

// ------- QKV reduce: Z-partial sum + bias + RoPE(+scale) + V-transpose -----
template<int Z>
__global__ __launch_bounds__(256) void qkv_reduce_kernel(
    const u16* __restrict__ part,
    const float* __restrict__ q_b, const float* __restrict__ k_b,
    const float* __restrict__ v_b,
    const float* __restrict__ cosb, const float* __restrict__ sinb,
    u16* __restrict__ qbuf, u16* __restrict__ kbuf, u16* __restrict__ vtb)
{
  const int s   = blockIdx.y;
  const int c   = blockIdx.x * 256 + threadIdx.x;   // 0..2303
  const int seg = c >> 6;
  const int d   = c & 63;
  const u16* pr = part + (size_t)s * NQKV;

  int base, bb;
  const float* bias;
  if (seg < 28)      { base = seg * 128;              bb = base; bias = q_b; }
  else if (seg < 32) { base = HID + (seg - 28) * 128; bb = (seg - 28) * 128; bias = k_b; }
  else               { base = HID + KVD + (seg - 32) * 128; bb = (seg - 32) * 128; bias = v_b; }

  float lo = bias[bb + d];
  float hi = bias[bb + d + 64];
#pragma unroll
  for (int z = 0; z < Z; ++z) {
    lo += bf2f(pr[(size_t)z * S_LEN * NQKV + base + d]);
    hi += bf2f(pr[(size_t)z * S_LEN * NQKV + base + d + 64]);
  }

  if (seg < 28) {
    const float cc = cosb[s * HD + d];
    const float ss = sinb[s * HD + d];
    qbuf[(size_t)s * HID + bb + d]      = f2bf((lo * cc - hi * ss) * QK_SCALE_L2E);
    qbuf[(size_t)s * HID + bb + d + 64] = f2bf((lo * ss + hi * cc) * QK_SCALE_L2E);
  } else if (seg < 32) {
    const float cc = cosb[s * HD + d];
    const float ss = sinb[s * HD + d];
    kbuf[(size_t)s * KVD + bb + d]      = f2bf(lo * cc - hi * ss);
    kbuf[(size_t)s * KVD + bb + d + 64] = f2bf(lo * ss + hi * cc);
  } else {
    vtb[(size_t)(bb + d) * S_LEN + s]      = f2bf(lo);
    vtb[(size_t)(bb + d + 64) * S_LEN + s] = f2bf(hi);
  }
}

// ------- O-proj reduce: f32 out = p0 + p1 -------
__global__ __launch_bounds__(256) void o_reduce_kernel(
    const u16* __restrict__ part, float* __restrict__ out)
{
  const int i = blockIdx.x * 256 + threadIdx.x;   // 4 elems each
  const uint2 a = ((const uint2*)part)[i];
  const uint2 b = ((const uint2*)(part + (size_t)S_LEN * HID))[i];
  float4 o;
  o.x = bf2f((u16)(a.x & 0xffff)) + bf2f((u16)(b.x & 0xffff));
  o.y = bf2f((u16)(a.x >> 16))    + bf2f((u16)(b.x >> 16));
  o.z = bf2f((u16)(a.y & 0xffff)) + bf2f((u16)(b.y & 0xffff));
  o.w = bf2f((u16)(a.y >> 16))    + bf2f((u16)(b.y >> 16));
  ((float4*)out)[i] = o;
}

// ---------------- Flash attention (causal, GQA) ----------------
// R11 structure (proven best): 256 thr, 4 waves x 16 q-rows, paired lo/hi
// tiles (33 uniform KV iters), dbuf K/V prefetch-before-compute, ones-MFMA
// row-sum, native cvt, thread-local defer-max trigger. Do not touch.
__global__ __launch_bounds__(256) void attn_kernel(
    const u16* __restrict__ qb, const u16* __restrict__ kb,
    const u16* __restrict__ vtb, u16* __restrict__ ao)
{
  __shared__ u16 Ks[2][64 * 128];   // [kv][d], swizzled
  __shared__ u16 Vts[2][128 * 64];  // [d][kv], swizzled
  __shared__ u16 Ps[4][16 * 64];    // per-wave P, swizzled

  const int h   = blockIdx.y;
  const int kvh = h / REP;
  const int lo  = blockIdx.x;       // 0..15
  const int hi  = 31 - lo;
  const int t   = threadIdx.x;
  const int w   = t >> 6;
  const int l   = t & 63;
  const int lr  = l & 15;
  const int lg  = l >> 4;
  const int sw  = (lr & 7) << 3;
  const f32x4 fz = {0.f, 0.f, 0.f, 0.f};
  short8 onesv;
#pragma unroll
  for (int i = 0; i < 8; ++i) onesv[i] = (short)0x3F80;  // bf16 1.0

  const u16* kbh  = kb + kvh * HD;
  const u16* vtbh = vtb + (size_t)kvh * HD * S_LEN;

  int tile = lo;
  short8 qf[4];
  {
    const u16* qrow = qb + (size_t)(tile * 64 + w * 16 + lr) * HID + h * HD;
#pragma unroll
    for (int dk = 0; dk < 4; ++dk)
      qf[dk] = *(const short8*)(qrow + dk * 32 + lg * 8);
  }

  float m_r[4];
  f32x4 lacc;       // row-sum accumulator via ones-MFMA
  f32x4 o_acc[8];
#pragma unroll
  for (int r = 0; r < 4; ++r) m_r[r] = -1e30f;
  lacc = fz;
#pragma unroll
  for (int db = 0; db < 8; ++db) o_acc[db] = fz;

  // ---- prologue: stage kv tile 0 into buf 0 ----
#pragma unroll
  for (int i = 0; i < 4; ++i) {
    const int e  = (i * 256 + t) * 8;
    const int rk = e >> 7;
    const int ck = (e & 127) ^ ((rk & 7) << 3);
    GLL16(kbh + (size_t)rk * KVD + ck, &Ks[0][0] + e);
    const int rv = e >> 6;
    const int cv = (e & 63) ^ ((rv & 7) << 3);
    GLL16(vtbh + (size_t)rv * S_LEN + cv, &Vts[0][0] + e);
  }
  __syncthreads();

#pragma unroll 1
  for (int j = 0; j < 33; ++j) {
    const int buf = j & 1;
    // ---- issue prefetch of next kv tile into buf^1 ----
    if (j + 1 < 33) {
      const int jn  = j + 1;
      const int kvn = ((jn <= lo) ? jn : (jn - lo - 1)) * 64;
#pragma unroll
      for (int i = 0; i < 4; ++i) {
        const int e  = (i * 256 + t) * 8;
        const int rk = e >> 7;
        const int ck = (e & 127) ^ ((rk & 7) << 3);
        GLL16(kbh + (size_t)(kvn + rk) * KVD + ck, &Ks[buf ^ 1][0] + e);
        const int rv = e >> 6;
        const int cv = (e & 63) ^ ((rv & 7) << 3);
        GLL16(vtbh + (size_t)rv * S_LEN + kvn + cv, &Vts[buf ^ 1][0] + e);
      }
    }

    const int kv0 = ((j <= lo) ? j : (j - lo - 1)) * 64;
    const u16* ks = &Ks[buf][0];
    const u16* vs = &Vts[buf][0];

    // ---- QK^T : S[16 q x 64 kv] per wave ----
    f32x4 sacc[4];
#pragma unroll
    for (int kvt = 0; kvt < 4; ++kvt) sacc[kvt] = fz;
    __builtin_amdgcn_s_setprio(1);
#pragma unroll
    for (int kvt = 0; kvt < 4; ++kvt) {
#pragma unroll
      for (int dk = 0; dk < 4; ++dk) {
        const short8 kf = *(const short8*)(ks + (kvt * 16 + lr) * 128 + ((dk * 32 + lg * 8) ^ sw));
        sacc[kvt] = __builtin_amdgcn_mfma_f32_16x16x32_bf16(qf[dk], kf, sacc[kvt], 0, 0, 0);
      }
    }
    __builtin_amdgcn_s_setprio(0);

    const bool last_of_half = (j == lo) || (j == 32);
    if (last_of_half) {  // diagonal tile: causal mask
      const int q0w = tile * 64 + w * 16;
#pragma unroll
      for (int kvt = 0; kvt < 4; ++kvt) {
        const int col = kv0 + kvt * 16 + lr;
#pragma unroll
        for (int r = 0; r < 4; ++r) {
          if (col > q0w + lg * 4 + r) sacc[kvt][r] = -1e30f;
        }
      }
    }

    // ---- online softmax: THREAD-LOCAL defer-max trigger (THR=8) ----
    float lm[4];
    bool ok = true;
#pragma unroll
    for (int r = 0; r < 4; ++r) {
      lm[r] = fmaxf(fmaxf(sacc[0][r], sacc[1][r]), fmaxf(sacc[2][r], sacc[3][r]));
      ok = ok && (lm[r] <= m_r[r] + 8.f);
    }
    if (!__all(ok)) {   // rare: full cross-lane reduce + rescale
#pragma unroll
      for (int r = 0; r < 4; ++r) {
        float tm = lm[r];
        tm = fmaxf(tm, __shfl_xor(tm, 1));
        tm = fmaxf(tm, __shfl_xor(tm, 2));
        tm = fmaxf(tm, __shfl_xor(tm, 4));
        tm = fmaxf(tm, __shfl_xor(tm, 8));
        const float mn = fmaxf(m_r[r], tm);
        const float alpha = exp2f(m_r[r] - mn);
        m_r[r] = mn;
        lacc[r] *= alpha;
#pragma unroll
        for (int db = 0; db < 8; ++db) o_acc[db][r] *= alpha;
      }
    }

    // ---- P = exp2(S - m) -> per-wave LDS (bf16, swizzled) ----
#pragma unroll
    for (int kvt = 0; kvt < 4; ++kvt) {
#pragma unroll
      for (int r = 0; r < 4; ++r) {
        const int prow = lg * 4 + r;
        Ps[w][prow * 64 + ((kvt * 16 + lr) ^ ((prow & 7) << 3))] =
            nbf(exp2f(sacc[kvt][r] - m_r[r]));
      }
    }

    short8 pf[2];
#pragma unroll
    for (int ks2 = 0; ks2 < 2; ++ks2)
      pf[ks2] = *(const short8*)(&Ps[w][0] + lr * 64 + ((ks2 * 32 + lg * 8) ^ sw));

    // ---- PV (+ ones-column MFMA row-sum) ----
    __builtin_amdgcn_s_setprio(1);
    lacc = __builtin_amdgcn_mfma_f32_16x16x32_bf16(pf[0], onesv, lacc, 0, 0, 0);
    lacc = __builtin_amdgcn_mfma_f32_16x16x32_bf16(pf[1], onesv, lacc, 0, 0, 0);
#pragma unroll
    for (int db = 0; db < 8; ++db) {
#pragma unroll
      for (int ks2 = 0; ks2 < 2; ++ks2) {
        const short8 vf = *(const short8*)(vs + (db * 16 + lr) * 64 + ((ks2 * 32 + lg * 8) ^ sw));
        o_acc[db] = __builtin_amdgcn_mfma_f32_16x16x32_bf16(pf[ks2], vf, o_acc[db], 0, 0, 0);
      }
    }
    __builtin_amdgcn_s_setprio(0);

    // ---- end-of-half: epilogue + switch to hi tile ----
    if (last_of_half) {
#pragma unroll
      for (int r = 0; r < 4; ++r) {
        const float inv = 1.0f / lacc[r];
        u16* orow = ao + (size_t)(tile * 64 + w * 16 + lg * 4 + r) * HID + h * HD;
#pragma unroll
        for (int db = 0; db < 8; ++db)
          orow[db * 16 + lr] = nbf(o_acc[db][r] * inv);
      }
      if (j != 32) {
        tile = hi;
        const u16* qrow = qb + (size_t)(tile * 64 + w * 16 + lr) * HID + h * HD;
#pragma unroll
        for (int dk = 0; dk < 4; ++dk)
          qf[dk] = *(const short8*)(qrow + dk * 32 + lg * 8);
#pragma unroll
        for (int r = 0; r < 4; ++r) m_r[r] = -1e30f;
        lacc = fz;
#pragma unroll
        for (int db = 0; db < 8; ++db) o_acc[db] = fz;
      }
    }
    __syncthreads();  // drains prefetch + guards buf reuse
  }
}

// ---------------- launch ----------------
extern "C" void kernel_launch(void* const* d_in, const int* in_sizes, int n_in,
                              void* d_out, int out_size, void* d_ws, size_t ws_size,
                              hipStream_t stream) {
  const float* hidden = (const float*)d_in[0];
  const float* cosb = (const float*)d_in[2];
  const float* sinb = (const float*)d_in[3];
  const float* q_w  = (const float*)d_in[4];
  const float* q_b  = (const float*)d_in[5];
  const float* k_w  = (const float*)d_in[6];
  const float* k_b  = (const float*)d_in[7];
  const float* v_w  = (const float*)d_in[8];
  const float* v_b  = (const float*)d_in[9];
  const float* o_w  = (const float*)d_in[10];
  float* out = (float*)d_out;

  char* p = (char*)d_ws;
  u16* hb   = (u16*)p; p += (size_t)S_LEN * HID * 2;
  u16* qwb  = (u16*)p; p += (size_t)HID * HID * 2;
  u16* kwb  = (u16*)p; p += (size_t)KVD * HID * 2;
  u16* vwb  = (u16*)p; p += (size_t)KVD * HID * 2;
  u16* owb  = (u16*)p; p += (size_t)HID * HID * 2;
  u16* qbuf = (u16*)p; p += (size_t)S_LEN * HID * 2;
  u16* kbuf = (u16*)p; p += (size_t)S_LEN * KVD * 2;
  u16* vtb  = (u16*)p; p += (size_t)KVD * S_LEN * 2;
  u16* ao   = (u16*)p; p += (size_t)S_LEN * HID * 2;
  u16* part = (u16*)p;
  const size_t base = (size_t)(p - (char*)d_ws);
  // z=4 qkv partials need 4*S*NQKV*2 bytes; fall back to z=2 if ws is short.
  const int zq = (base + (size_t)4 * S_LEN * NQKV * 2 <= ws_size) ? 4 : 2;
  if (base + (size_t)zq * S_LEN * NQKV * 2 > ws_size) return;

  cvt_all_kernel<<<dim3(1024, 5), 256, 0, stream>>>(
      hidden, q_w, k_w, v_w, o_w, hb, qwb, kwb, vwb, owb);

  qkv_gemm_kernel<<<dim3(16, 18, zq), 512, 0, stream>>>(hb, qwb, kwb, vwb, part);
  if (zq == 4)
    qkv_reduce_kernel<4><<<dim3(9, S_LEN), 256, 0, stream>>>(
        part, q_b, k_b, v_b, cosb, sinb, qbuf, kbuf, vtb);
  else
    qkv_reduce_kernel<2><<<dim3(9, S_LEN), 256, 0, stream>>>(
        part, q_b, k_b, v_b, cosb, sinb, qbuf, kbuf, vtb);

  attn_kernel<<<dim3(16, 28), 256, 0, stream>>>(qbuf, kbuf, vtb, ao);

  oproj_gemm_kernel<<<dim3(16, 14, 2), 512, 0, stream>>>(ao, owb, part);
  o_reduce_kernel<<<(S_LEN * HID / 4) / 256, 256, 0, stream>>>(part, out);
}

// Round 14
// 287.505 us; speedup vs baseline: 1.0176x; 1.0176x over previous
//
#include <hip/hip_runtime.h>
#include <hip/hip_bf16.h>
#include <stdint.h>
#include <stddef.h>

#define S_LEN 2048
#define HID   3584
#define NH    28
#define NKV   4
#define HD    128
#define REP   7
#define KVD   512
#define NQKV  4608          // 3584 + 512 + 512
#define KSPLIT_LEN 1792     // 3584 / 2
// QK scale with log2(e) folded in: softmax uses exp2
#define QK_SCALE_L2E 0.12752462155f   // (1/sqrt(128)) * log2(e)

typedef unsigned short u16;
typedef short short8 __attribute__((ext_vector_type(8)));
typedef float f32x4 __attribute__((ext_vector_type(4)));

__device__ __forceinline__ u16 f2bf(float f) {
  union { float f; uint32_t u; } v; v.f = f;
  uint32_t r = v.u + 0x7fffu + ((v.u >> 16) & 1u);
  return (u16)(r >> 16);
}
__device__ __forceinline__ float bf2f(u16 u) {
  union { uint32_t u; float f; } v; v.u = ((uint32_t)u) << 16;
  return v.f;
}
__device__ __forceinline__ u16 nbf(float f) {  // native 1-op RNE cvt
  __hip_bfloat16 h = __float2bfloat16(f);
  return *reinterpret_cast<u16*>(&h);
}

#define GLL16(gp, lp) __builtin_amdgcn_global_load_lds( \
    (const __attribute__((address_space(1))) void*)(gp), \
    (__attribute__((address_space(3))) void*)(lp), 16, 0, 0)

// ---------------- f32 -> bf16 bulk convert (all 5 buffers, one launch) -------
__global__ __launch_bounds__(256) void cvt_all_kernel(
    const float* __restrict__ h, const float* __restrict__ qw,
    const float* __restrict__ kw, const float* __restrict__ vw,
    const float* __restrict__ ow,
    u16* __restrict__ hb, u16* __restrict__ qwb, u16* __restrict__ kwb,
    u16* __restrict__ vwb, u16* __restrict__ owb)
{
  const float* src; u16* dst; int n4;
  switch (blockIdx.y) {
    case 0: src = h;  dst = hb;  n4 = S_LEN * HID / 4; break;
    case 1: src = qw; dst = qwb; n4 = HID * HID / 4;   break;
    case 2: src = kw; dst = kwb; n4 = KVD * HID / 4;   break;
    case 3: src = vw; dst = vwb; n4 = KVD * HID / 4;   break;
    default: src = ow; dst = owb; n4 = HID * HID / 4;  break;
  }
  int i = blockIdx.x * blockDim.x + threadIdx.x;
  const int stride = gridDim.x * blockDim.x;
  for (; i < n4; i += stride) {
    float4 v = reinterpret_cast<const float4*>(src)[i];
    uint2 o;
    o.x = (uint32_t)f2bf(v.x) | ((uint32_t)f2bf(v.y) << 16);
    o.y = (uint32_t)f2bf(v.z) | ((uint32_t)f2bf(v.w) << 16);
    reinterpret_cast<uint2*>(dst)[i] = o;
  }
}

// ---- GEMM core: 128x256 tile, 8 waves (2Mx4N, wave=64x64), BK=32,
// triple-buffered LDS (12KB/buf -> 36KB... x2 blocks/CU), counted
// vmcnt (3 loads/thread/tile in flight; vmcnt(0) only at tail).
__device__ __forceinline__ void gemm_core_128x256_bk32(
    u16* lds, const u16* __restrict__ A, const u16* __restrict__ W,
    u16* __restrict__ C, int ldC, int lda, int T)
{
  const int t  = threadIdx.x;       // 0..511
  const int l  = t & 63;
  const int w  = t >> 6;            // 0..7
  const int lr = l & 15;
  const int lg = l >> 4;
  const int wm = (w >> 2) << 6;     // 0 or 64
  const int wn = (w & 3) << 6;      // 0,64,128,192
  const int sw = (((lr & 3) ^ ((lr >> 2) & 3)) << 3);

  const f32x4 fz = {0.f, 0.f, 0.f, 0.f};
  f32x4 acc[4][4];
#pragma unroll
  for (int i = 0; i < 4; ++i)
#pragma unroll
    for (int j = 0; j < 4; ++j) acc[i][j] = fz;

#define SWZC(e) ((e & 31) ^ ((((e >> 5) & 3) ^ ((e >> 7) & 3)) << 3))
#define STAGE3(kt, buf) do {                                          \
    { const int e_ = t * 8;                                           \
      const int r_ = e_ >> 5;  const int c_ = SWZC(e_);               \
      GLL16(A + (size_t)(kt) * 32 + (size_t)r_ * lda + c_, (buf) + e_); } \
    _Pragma("unroll")                                                 \
    for (int i_ = 0; i_ < 2; ++i_) {                                  \
      const int e_ = (i_ * 512 + t) * 8;                              \
      const int r_ = e_ >> 5;  const int c_ = SWZC(e_);               \
      GLL16(W + (size_t)(kt) * 32 + (size_t)r_ * lda + c_, (buf) + 4096 + e_); } \
  } while (0)

  STAGE3(0, lds);
  STAGE3(1, lds + 12288);

#pragma unroll 1
  for (int tk = 0; tk < T; ++tk) {
    if (tk + 1 < T) { asm volatile("s_waitcnt vmcnt(3)" ::: "memory"); }
    else            { asm volatile("s_waitcnt vmcnt(0)" ::: "memory"); }
    __builtin_amdgcn_sched_barrier(0);
    __builtin_amdgcn_s_barrier();
    __builtin_amdgcn_sched_barrier(0);

    if (tk + 2 < T) {
      u16* nb = lds + ((tk + 2) % 3) * 12288;
      STAGE3(tk + 2, nb);
    }

    const u16* As_ = lds + (tk % 3) * 12288;
    const u16* Bs_ = As_ + 4096;
    short8 af[4], bfr[4];
#pragma unroll
    for (int mi = 0; mi < 4; ++mi)
      af[mi] = *(const short8*)(As_ + (wm + mi * 16 + lr) * 32 + ((lg * 8) ^ sw));
#pragma unroll
    for (int ni = 0; ni < 4; ++ni)
      bfr[ni] = *(const short8*)(Bs_ + (wn + ni * 16 + lr) * 32 + ((lg * 8) ^ sw));
    __builtin_amdgcn_s_setprio(1);
#pragma unroll
    for (int mi = 0; mi < 4; ++mi)
#pragma unroll
      for (int ni = 0; ni < 4; ++ni)
        acc[mi][ni] = __builtin_amdgcn_mfma_f32_16x16x32_bf16(af[mi], bfr[ni], acc[mi][ni], 0, 0, 0);
    __builtin_amdgcn_s_setprio(0);
  }
#undef STAGE3
#undef SWZC

#pragma unroll
  for (int ni = 0; ni < 4; ++ni) {
    const int n = wn + ni * 16 + lr;
#pragma unroll
    for (int mi = 0; mi < 4; ++mi) {
#pragma unroll
      for (int r = 0; r < 4; ++r) {
        const int m = wm + mi * 16 + lg * 4 + r;
        C[(size_t)m * ldC + n] = f2bf(acc[mi][ni][r]);
      }
    }
  }
}

// QKV: partials [2][S][NQKV]; grid (16, 18, 2); XCD-chunk swizzle (288=8*36)
__global__ __launch_bounds__(512) void qkv_gemm_kernel(
    const u16* __restrict__ hb,
    const u16* __restrict__ qwb, const u16* __restrict__ kwb, const u16* __restrict__ vwb,
    u16* __restrict__ part)
{
  __shared__ u16 lds[3 * 12288];
  const int lin = blockIdx.y * 16 + blockIdx.x;   // 0..287, dispatch-linear
  const int swz = (lin & 7) * 36 + (lin >> 3);    // bijective XCD chunking
  const int m0  = (swz & 15) * 128;
  const int by  = swz >> 4;                       // 0..17
  const int k0  = blockIdx.z * KSPLIT_LEN;
  u16* Cz = part + (size_t)blockIdx.z * S_LEN * NQKV;
  const u16* Wp; size_t coff; int n0;
  if (by < 14)      { Wp = qwb; n0 = by * 256;        coff = n0; }
  else if (by < 16) { Wp = kwb; n0 = (by - 14) * 256; coff = HID + n0; }
  else              { Wp = vwb; n0 = (by - 16) * 256; coff = HID + KVD + n0; }
  gemm_core_128x256_bk32(lds, hb + (size_t)m0 * HID + k0,
                         Wp + (size_t)n0 * HID + k0,
                         Cz + (size_t)m0 * NQKV + coff, NQKV, HID, KSPLIT_LEN / 32);
}

// O-proj: partials [2][S][HID]; grid (16, 14, 2); XCD swizzle (224=8*28)
__global__ __launch_bounds__(512) void oproj_gemm_kernel(
    const u16* __restrict__ ao, const u16* __restrict__ owb, u16* __restrict__ part)
{
  __shared__ u16 lds[3 * 12288];
  const int lin = blockIdx.y * 16 + blockIdx.x;   // 0..223
  const int swz = (lin & 7) * 28 + (lin >> 3);
  const int m0  = (swz & 15) * 128;
  const int n0  = (swz >> 4) * 256;
  const int k0  = blockIdx.z * KSPLIT_LEN;
  u16* Cz = part + (size_t)blockIdx.z * S_LEN * HID;
  gemm_core_128x256_bk32(lds, ao + (size_t)m0 * HID + k0,
                         owb + (size_t)n0 * HID + k0,
                         Cz + (size_t)m0 * HID + n0, HID, HID, KSPLIT_LEN / 32);
}

// ------- QKV reduce: partial sum + bias + RoPE(+scale) + V-transpose -------
template<int Z>
__global__ __launch_bounds__(256) void qkv_reduce_kernel(
    const u16* __restrict__ part,
    const float* __restrict__ q_b, const float* __restrict__ k_b,
    const float* __restrict__ v_b,
    const float* __restrict__ cosb, const float* __restrict__ sinb,
    u16* __restrict__ qbuf, u16* __restrict__ kbuf, u16* __restrict__ vtb)
{
  const int s   = blockIdx.y;
  const int c   = blockIdx.x * 256 + threadIdx.x;   // 0..2303
  const int seg = c >> 6;
  const int d   = c & 63;
  const u16* pr = part + (size_t)s * NQKV;

  int base, bb;
  const float* bias;
  if (seg < 28)      { base = seg * 128;              bb = base; bias = q_b; }
  else if (seg < 32) { base = HID + (seg - 28) * 128; bb = (seg - 28) * 128; bias = k_b; }
  else               { base = HID + KVD + (seg - 32) * 128; bb = (seg - 32) * 128; bias = v_b; }

  float lo = bias[bb + d];
  float hi = bias[bb + d + 64];
#pragma unroll
  for (int z = 0; z < Z; ++z) {
    lo += bf2f(pr[(size_t)z * S_LEN * NQKV + base + d]);
    hi += bf2f(pr[(size_t)z * S_LEN * NQKV + base + d + 64]);
  }

  if (seg < 28) {
    const float cc = cosb[s * HD + d];
    const float ss = sinb[s * HD + d];
    qbuf[(size_t)s * HID + bb + d]      = f2bf((lo * cc - hi * ss) * QK_SCALE_L2E);
    qbuf[(size_t)s * HID + bb + d + 64] = f2bf((lo * ss + hi * cc) * QK_SCALE_L2E);
  } else if (seg < 32) {
    const float cc = cosb[s * HD + d];
    const float ss = sinb[s * HD + d];
    kbuf[(size_t)s * KVD + bb + d]      = f2bf(lo * cc - hi * ss);
    kbuf[(size_t)s * KVD + bb + d + 64] = f2bf(lo * ss + hi * cc);
  } else {
    vtb[(size_t)(bb + d) * S_LEN + s]      = f2bf(lo);
    vtb[(size_t)(bb + d + 64) * S_LEN + s] = f2bf(hi);
  }
}

// ------- O-proj reduce: f32 out = p0 + p1 -------
__global__ __launch_bounds__(256) void o_reduce_kernel(
    const u16* __restrict__ part, float* __restrict__ out)
{
  const int i = blockIdx.x * 256 + threadIdx.x;   // 4 elems each
  const uint2 a = ((const uint2*)part)[i];
  const uint2 b = ((const uint2*)(part + (size_t)S_LEN * HID))[i];
  float4 o;
  o.x = bf2f((u16)(a.x & 0xffff)) + bf2f((u16)(b.x & 0xffff));
  o.y = bf2f((u16)(a.x >> 16))    + bf2f((u16)(b.x >> 16));
  o.z = bf2f((u16)(a.y & 0xffff)) + bf2f((u16)(b.y & 0xffff));
  o.w = bf2f((u16)(a.y >> 16))    + bf2f((u16)(b.y >> 16));
  ((float4*)out)[i] = o;
}

// ---------------- Flash attention (causal, GQA) ----------------
// R11 structure (proven best): 256 thr, 4 waves x 16 q-rows, paired lo/hi
// tiles (33 uniform KV iters), dbuf K/V prefetch-before-compute, ones-MFMA
// row-sum, native cvt, thread-local defer-max trigger.
__global__ __launch_bounds__(256) void attn_kernel(
    const u16* __restrict__ qb, const u16* __restrict__ kb,
    const u16* __restrict__ vtb, u16* __restrict__ ao)
{
  __shared__ u16 Ks[2][64 * 128];   // [kv][d], swizzled
  __shared__ u16 Vts[2][128 * 64];  // [d][kv], swizzled
  __shared__ u16 Ps[4][16 * 64];    // per-wave P, swizzled

  const int h   = blockIdx.y;
  const int kvh = h / REP;
  const int lo  = blockIdx.x;       // 0..15
  const int hi  = 31 - lo;
  const int t   = threadIdx.x;
  const int w   = t >> 6;
  const int l   = t & 63;
  const int lr  = l & 15;
  const int lg  = l >> 4;
  const int sw  = (lr & 7) << 3;
  const f32x4 fz = {0.f, 0.f, 0.f, 0.f};
  short8 onesv;
#pragma unroll
  for (int i = 0; i < 8; ++i) onesv[i] = (short)0x3F80;  // bf16 1.0

  const u16* kbh  = kb + kvh * HD;
  const u16* vtbh = vtb + (size_t)kvh * HD * S_LEN;

  int tile = lo;
  short8 qf[4];
  {
    const u16* qrow = qb + (size_t)(tile * 64 + w * 16 + lr) * HID + h * HD;
#pragma unroll
    for (int dk = 0; dk < 4; ++dk)
      qf[dk] = *(const short8*)(qrow + dk * 32 + lg * 8);
  }

  float m_r[4];
  f32x4 lacc;       // row-sum accumulator via ones-MFMA
  f32x4 o_acc[8];
#pragma unroll
  for (int r = 0; r < 4; ++r) m_r[r] = -1e30f;
  lacc = fz;
#pragma unroll
  for (int db = 0; db < 8; ++db) o_acc[db] = fz;

  // ---- prologue: stage kv tile 0 into buf 0 ----
#pragma unroll
  for (int i = 0; i < 4; ++i) {
    const int e  = (i * 256 + t) * 8;
    const int rk = e >> 7;
    const int ck = (e & 127) ^ ((rk & 7) << 3);
    GLL16(kbh + (size_t)rk * KVD + ck, &Ks[0][0] + e);
    const int rv = e >> 6;
    const int cv = (e & 63) ^ ((rv & 7) << 3);
    GLL16(vtbh + (size_t)rv * S_LEN + cv, &Vts[0][0] + e);
  }
  __syncthreads();

#pragma unroll 1
  for (int j = 0; j < 33; ++j) {
    const int buf = j & 1;
    // ---- issue prefetch of next kv tile into buf^1 ----
    if (j + 1 < 33) {
      const int jn  = j + 1;
      const int kvn = ((jn <= lo) ? jn : (jn - lo - 1)) * 64;
#pragma unroll
      for (int i = 0; i < 4; ++i) {
        const int e  = (i * 256 + t) * 8;
        const int rk = e >> 7;
        const int ck = (e & 127) ^ ((rk & 7) << 3);
        GLL16(kbh + (size_t)(kvn + rk) * KVD + ck, &Ks[buf ^ 1][0] + e);
        const int rv = e >> 6;
        const int cv = (e & 63) ^ ((rv & 7) << 3);
        GLL16(vtbh + (size_t)rv * S_LEN + kvn + cv, &Vts[buf ^ 1][0] + e);
      }
    }

    const int kv0 = ((j <= lo) ? j : (j - lo - 1)) * 64;
    const u16* ks = &Ks[buf][0];
    const u16* vs = &Vts[buf][0];

    // ---- QK^T : S[16 q x 64 kv] per wave ----
    f32x4 sacc[4];
#pragma unroll
    for (int kvt = 0; kvt < 4; ++kvt) sacc[kvt] = fz;
    __builtin_amdgcn_s_setprio(1);
#pragma unroll
    for (int kvt = 0; kvt < 4; ++kvt) {
#pragma unroll
      for (int dk = 0; dk < 4; ++dk) {
        const short8 kf = *(const short8*)(ks + (kvt * 16 + lr) * 128 + ((dk * 32 + lg * 8) ^ sw));
        sacc[kvt] = __builtin_amdgcn_mfma_f32_16x16x32_bf16(qf[dk], kf, sacc[kvt], 0, 0, 0);
      }
    }
    __builtin_amdgcn_s_setprio(0);

    const bool last_of_half = (j == lo) || (j == 32);
    if (last_of_half) {  // diagonal tile: causal mask
      const int q0w = tile * 64 + w * 16;
#pragma unroll
      for (int kvt = 0; kvt < 4; ++kvt) {
        const int col = kv0 + kvt * 16 + lr;
#pragma unroll
        for (int r = 0; r < 4; ++r) {
          if (col > q0w + lg * 4 + r) sacc[kvt][r] = -1e30f;
        }
      }
    }

    // ---- online softmax: THREAD-LOCAL defer-max trigger (THR=8) ----
    float lm[4];
    bool ok = true;
#pragma unroll
    for (int r = 0; r < 4; ++r) {
      lm[r] = fmaxf(fmaxf(sacc[0][r], sacc[1][r]), fmaxf(sacc[2][r], sacc[3][r]));
      ok = ok && (lm[r] <= m_r[r] + 8.f);
    }
    if (!__all(ok)) {   // rare: full cross-lane reduce + rescale
#pragma unroll
      for (int r = 0; r < 4; ++r) {
        float tm = lm[r];
        tm = fmaxf(tm, __shfl_xor(tm, 1));
        tm = fmaxf(tm, __shfl_xor(tm, 2));
        tm = fmaxf(tm, __shfl_xor(tm, 4));
        tm = fmaxf(tm, __shfl_xor(tm, 8));
        const float mn = fmaxf(m_r[r], tm);
        const float alpha = exp2f(m_r[r] - mn);
        m_r[r] = mn;
        lacc[r] *= alpha;
#pragma unroll
        for (int db = 0; db < 8; ++db) o_acc[db][r] *= alpha;
      }
    }

    // ---- P = exp2(S - m) -> per-wave LDS (bf16, swizzled) ----
#pragma unroll
    for (int kvt = 0; kvt < 4; ++kvt) {
#pragma unroll
      for (int r = 0; r < 4; ++r) {
        const int prow = lg * 4 + r;
        Ps[w][prow * 64 + ((kvt * 16 + lr) ^ ((prow & 7) << 3))] =
            nbf(exp2f(sacc[kvt][r] - m_r[r]));
      }
    }

    short8 pf[2];
#pragma unroll
    for (int ks2 = 0; ks2 < 2; ++ks2)
      pf[ks2] = *(const short8*)(&Ps[w][0] + lr * 64 + ((ks2 * 32 + lg * 8) ^ sw));

    // ---- PV (+ ones-column MFMA row-sum) ----
    __builtin_amdgcn_s_setprio(1);
    lacc = __builtin_amdgcn_mfma_f32_16x16x32_bf16(pf[0], onesv, lacc, 0, 0, 0);
    lacc = __builtin_amdgcn_mfma_f32_16x16x32_bf16(pf[1], onesv, lacc, 0, 0, 0);
#pragma unroll
    for (int db = 0; db < 8; ++db) {
#pragma unroll
      for (int ks2 = 0; ks2 < 2; ++ks2) {
        const short8 vf = *(const short8*)(vs + (db * 16 + lr) * 64 + ((ks2 * 32 + lg * 8) ^ sw));
        o_acc[db] = __builtin_amdgcn_mfma_f32_16x16x32_bf16(pf[ks2], vf, o_acc[db], 0, 0, 0);
      }
    }
    __builtin_amdgcn_s_setprio(0);

    // ---- end-of-half: epilogue + switch to hi tile ----
    if (last_of_half) {
#pragma unroll
      for (int r = 0; r < 4; ++r) {
        const float inv = 1.0f / lacc[r];
        u16* orow = ao + (size_t)(tile * 64 + w * 16 + lg * 4 + r) * HID + h * HD;
#pragma unroll
        for (int db = 0; db < 8; ++db)
          orow[db * 16 + lr] = nbf(o_acc[db][r] * inv);
      }
      if (j != 32) {
        tile = hi;
        const u16* qrow = qb + (size_t)(tile * 64 + w * 16 + lr) * HID + h * HD;
#pragma unroll
        for (int dk = 0; dk < 4; ++dk)
          qf[dk] = *(const short8*)(qrow + dk * 32 + lg * 8);
#pragma unroll
        for (int r = 0; r < 4; ++r) m_r[r] = -1e30f;
        lacc = fz;
#pragma unroll
        for (int db = 0; db < 8; ++db) o_acc[db] = fz;
      }
    }
    __syncthreads();  // drains prefetch + guards buf reuse
  }
}

// ---------------- launch ----------------
extern "C" void kernel_launch(void* const* d_in, const int* in_sizes, int n_in,
                              void* d_out, int out_size, void* d_ws, size_t ws_size,
                              hipStream_t stream) {
  const float* hidden = (const float*)d_in[0];
  const float* cosb = (const float*)d_in[2];
  const float* sinb = (const float*)d_in[3];
  const float* q_w  = (const float*)d_in[4];
  const float* q_b  = (const float*)d_in[5];
  const float* k_w  = (const float*)d_in[6];
  const float* k_b  = (const float*)d_in[7];
  const float* v_w  = (const float*)d_in[8];
  const float* v_b  = (const float*)d_in[9];
  const float* o_w  = (const float*)d_in[10];
  float* out = (float*)d_out;

  char* p = (char*)d_ws;
  u16* hb   = (u16*)p; p += (size_t)S_LEN * HID * 2;
  u16* qwb  = (u16*)p; p += (size_t)HID * HID * 2;
  u16* kwb  = (u16*)p; p += (size_t)KVD * HID * 2;
  u16* vwb  = (u16*)p; p += (size_t)KVD * HID * 2;
  u16* owb  = (u16*)p; p += (size_t)HID * HID * 2;
  u16* qbuf = (u16*)p; p += (size_t)S_LEN * HID * 2;
  u16* kbuf = (u16*)p; p += (size_t)S_LEN * KVD * 2;
  u16* vtb  = (u16*)p; p += (size_t)KVD * S_LEN * 2;
  u16* ao   = (u16*)p; p += (size_t)S_LEN * HID * 2;
  u16* part = (u16*)p; p += (size_t)2 * S_LEN * NQKV * 2;  // shared qkv/oproj partials
  if ((size_t)(p - (char*)d_ws) > ws_size) return;

  cvt_all_kernel<<<dim3(1024, 5), 256, 0, stream>>>(
      hidden, q_w, k_w, v_w, o_w, hb, qwb, kwb, vwb, owb);

  qkv_gemm_kernel<<<dim3(16, 18, 2), 512, 0, stream>>>(hb, qwb, kwb, vwb, part);
  qkv_reduce_kernel<2><<<dim3(9, S_LEN), 256, 0, stream>>>(
      part, q_b, k_b, v_b, cosb, sinb, qbuf, kbuf, vtb);

  attn_kernel<<<dim3(16, 28), 256, 0, stream>>>(qbuf, kbuf, vtb, ao);

  oproj_gemm_kernel<<<dim3(16, 14, 2), 512, 0, stream>>>(ao, owb, part);
  o_reduce_kernel<<<(S_LEN * HID / 4) / 256, 256, 0, stream>>>(part, out);
}

// Round 16
// 282.179 us; speedup vs baseline: 1.0368x; 1.0189x over previous
//
#include <hip/hip_runtime.h>
#include <hip/hip_bf16.h>
#include <stdint.h>
#include <stddef.h>

#define S_LEN 2048
#define HID   3584
#define NH    28
#define NKV   4
#define HD    128
#define REP   7
#define KVD   512
#define NQKV  4608          // 3584 + 512 + 512
#define KSPLIT_LEN 1792     // 3584 / 2 (oproj)
// QK scale with log2(e) folded in: softmax uses exp2
#define QK_SCALE_L2E 0.12752462155f   // (1/sqrt(128)) * log2(e)

typedef unsigned short u16;
typedef short short8 __attribute__((ext_vector_type(8)));
typedef float f32x4 __attribute__((ext_vector_type(4)));

__device__ __forceinline__ u16 f2bf(float f) {
  union { float f; uint32_t u; } v; v.f = f;
  uint32_t r = v.u + 0x7fffu + ((v.u >> 16) & 1u);
  return (u16)(r >> 16);
}
__device__ __forceinline__ float bf2f(u16 u) {
  union { uint32_t u; float f; } v; v.u = ((uint32_t)u) << 16;
  return v.f;
}
__device__ __forceinline__ u16 nbf(float f) {  // native 1-op RNE cvt
  __hip_bfloat16 h = __float2bfloat16(f);
  return *reinterpret_cast<u16*>(&h);
}

#define GLL16(gp, lp) __builtin_amdgcn_global_load_lds( \
    (const __attribute__((address_space(1))) void*)(gp), \
    (__attribute__((address_space(3))) void*)(lp), 16, 0, 0)

// ---------------- f32 -> bf16 bulk convert (all 5 buffers, one launch) -------
__global__ __launch_bounds__(256) void cvt_all_kernel(
    const float* __restrict__ h, const float* __restrict__ qw,
    const float* __restrict__ kw, const float* __restrict__ vw,
    const float* __restrict__ ow,
    u16* __restrict__ hb, u16* __restrict__ qwb, u16* __restrict__ kwb,
    u16* __restrict__ vwb, u16* __restrict__ owb)
{
  const float* src; u16* dst; int n4;
  switch (blockIdx.y) {
    case 0: src = h;  dst = hb;  n4 = S_LEN * HID / 4; break;
    case 1: src = qw; dst = qwb; n4 = HID * HID / 4;   break;
    case 2: src = kw; dst = kwb; n4 = KVD * HID / 4;   break;
    case 3: src = vw; dst = vwb; n4 = KVD * HID / 4;   break;
    default: src = ow; dst = owb; n4 = HID * HID / 4;  break;
  }
  int i = blockIdx.x * blockDim.x + threadIdx.x;
  const int stride = gridDim.x * blockDim.x;
  for (; i < n4; i += stride) {
    float4 v = reinterpret_cast<const float4*>(src)[i];
    uint2 o;
    o.x = (uint32_t)f2bf(v.x) | ((uint32_t)f2bf(v.y) << 16);
    o.y = (uint32_t)f2bf(v.z) | ((uint32_t)f2bf(v.w) << 16);
    reinterpret_cast<uint2*>(dst)[i] = o;
  }
}

#define SWZC(e) ((e & 31) ^ ((((e >> 5) & 3) ^ ((e >> 7) & 3)) << 3))
#define STAGE3(kt, buf) do {                                          \
    { const int e_ = t * 8;                                           \
      const int r_ = e_ >> 5;  const int c_ = SWZC(e_);               \
      GLL16(A + (size_t)(kt) * 32 + (size_t)r_ * lda + c_, (buf) + e_); } \
    _Pragma("unroll")                                                 \
    for (int i_ = 0; i_ < 2; ++i_) {                                  \
      const int e_ = (i_ * 512 + t) * 8;                              \
      const int r_ = e_ >> 5;  const int c_ = SWZC(e_);               \
      GLL16(W + (size_t)(kt) * 32 + (size_t)r_ * lda + c_, (buf) + 4096 + e_); } \
  } while (0)

// ---- GEMM core (oproj): 128x256 tile, 8 waves, BK=32, triple-buffered LDS,
// counted vmcnt. Unchanged proven R11 core.
__device__ __forceinline__ void gemm_core_128x256_bk32(
    u16* lds, const u16* __restrict__ A, const u16* __restrict__ W,
    u16* __restrict__ C, int ldC, int lda, int T)
{
  const int t  = threadIdx.x;       // 0..511
  const int l  = t & 63;
  const int w  = t >> 6;            // 0..7
  const int lr = l & 15;
  const int lg = l >> 4;
  const int wm = (w >> 2) << 6;     // 0 or 64
  const int wn = (w & 3) << 6;      // 0,64,128,192
  const int sw = (((lr & 3) ^ ((lr >> 2) & 3)) << 3);

  const f32x4 fz = {0.f, 0.f, 0.f, 0.f};
  f32x4 acc[4][4];
#pragma unroll
  for (int i = 0; i < 4; ++i)
#pragma unroll
    for (int j = 0; j < 4; ++j) acc[i][j] = fz;

  STAGE3(0, lds);
  STAGE3(1, lds + 12288);

#pragma unroll 1
  for (int tk = 0; tk < T; ++tk) {
    if (tk + 1 < T) { asm volatile("s_waitcnt vmcnt(3)" ::: "memory"); }
    else            { asm volatile("s_waitcnt vmcnt(0)" ::: "memory"); }
    __builtin_amdgcn_sched_barrier(0);
    __builtin_amdgcn_s_barrier();
    __builtin_amdgcn_sched_barrier(0);

    if (tk + 2 < T) {
      u16* nb = lds + ((tk + 2) % 3) * 12288;
      STAGE3(tk + 2, nb);
    }

    const u16* As_ = lds + (tk % 3) * 12288;
    const u16* Bs_ = As_ + 4096;
    short8 af[4], bfr[4];
#pragma unroll
    for (int mi = 0; mi < 4; ++mi)
      af[mi] = *(const short8*)(As_ + (wm + mi * 16 + lr) * 32 + ((lg * 8) ^ sw));
#pragma unroll
    for (int ni = 0; ni < 4; ++ni)
      bfr[ni] = *(const short8*)(Bs_ + (wn + ni * 16 + lr) * 32 + ((lg * 8) ^ sw));
    __builtin_amdgcn_s_setprio(1);
#pragma unroll
    for (int mi = 0; mi < 4; ++mi)
#pragma unroll
      for (int ni = 0; ni < 4; ++ni)
        acc[mi][ni] = __builtin_amdgcn_mfma_f32_16x16x32_bf16(af[mi], bfr[ni], acc[mi][ni], 0, 0, 0);
    __builtin_amdgcn_s_setprio(0);
  }

#pragma unroll
  for (int ni = 0; ni < 4; ++ni) {
    const int n = wn + ni * 16 + lr;
#pragma unroll
    for (int mi = 0; mi < 4; ++mi) {
#pragma unroll
      for (int r = 0; r < 4; ++r) {
        const int m = wm + mi * 16 + lg * 4 + r;
        C[(size_t)m * ldC + n] = f2bf(acc[mi][ni][r]);
      }
    }
  }
}

// ---- QKV fused GEMM (z=1): same core loop, remapped B-fragments so that
// acc[mi][ni] / acc[mi][ni+2] form RoPE pairs (d, d+64) in the same lane.
// Epilogue: bias + RoPE(+scale) -> qbuf/kbuf; bias -> vbuf. No partials.
__global__ __launch_bounds__(512) void qkv_gemm_fused_kernel(
    const u16* __restrict__ hb,
    const u16* __restrict__ qwb, const u16* __restrict__ kwb, const u16* __restrict__ vwb,
    const float* __restrict__ q_b, const float* __restrict__ k_b,
    const float* __restrict__ v_b,
    const float* __restrict__ cosb, const float* __restrict__ sinb,
    u16* __restrict__ qbuf, u16* __restrict__ kbuf, u16* __restrict__ vbuf)
{
  __shared__ u16 lds[3 * 12288];
  const int lin = blockIdx.y * 16 + blockIdx.x;   // 0..287
  const int swz = (lin & 7) * 36 + (lin >> 3);    // bijective XCD chunking
  const int m0  = (swz & 15) * 128;
  const int by  = swz >> 4;                       // 0..17
  const int lda = HID;

  const u16* A = hb + (size_t)m0 * HID;
  const u16* W;
  if (by < 14)      W = qwb + (size_t)by * 256 * HID;
  else if (by < 16) W = kwb + (size_t)(by - 14) * 256 * HID;
  else              W = vwb + (size_t)(by - 16) * 256 * HID;

  const int t  = threadIdx.x;
  const int l  = t & 63;
  const int w  = t >> 6;
  const int lr = l & 15;
  const int lg = l >> 4;
  const int wm = (w >> 2) << 6;
  const int w4 = w & 3;
  const int sw = (((lr & 3) ^ ((lr >> 2) & 3)) << 3);

  int nbase[4];
#pragma unroll
  for (int ni = 0; ni < 4; ++ni)
    nbase[ni] = (w4 >> 1) * 128 + (w4 & 1) * 32 + (ni & 1) * 16 + (ni >> 1) * 64;

  const f32x4 fz = {0.f, 0.f, 0.f, 0.f};
  f32x4 acc[4][4];
#pragma unroll
  for (int i = 0; i < 4; ++i)
#pragma unroll
    for (int j = 0; j < 4; ++j) acc[i][j] = fz;

  STAGE3(0, lds);
  STAGE3(1, lds + 12288);

  const int T = HID / 32;   // 112
#pragma unroll 1
  for (int tk = 0; tk < T; ++tk) {
    if (tk + 1 < T) { asm volatile("s_waitcnt vmcnt(3)" ::: "memory"); }
    else            { asm volatile("s_waitcnt vmcnt(0)" ::: "memory"); }
    __builtin_amdgcn_sched_barrier(0);
    __builtin_amdgcn_s_barrier();
    __builtin_amdgcn_sched_barrier(0);

    if (tk + 2 < T) {
      u16* nb = lds + ((tk + 2) % 3) * 12288;
      STAGE3(tk + 2, nb);
    }

    const u16* As_ = lds + (tk % 3) * 12288;
    const u16* Bs_ = As_ + 4096;
    short8 af[4], bfr[4];
#pragma unroll
    for (int mi = 0; mi < 4; ++mi)
      af[mi] = *(const short8*)(As_ + (wm + mi * 16 + lr) * 32 + ((lg * 8) ^ sw));
#pragma unroll
    for (int ni = 0; ni < 4; ++ni)
      bfr[ni] = *(const short8*)(Bs_ + (nbase[ni] + lr) * 32 + ((lg * 8) ^ sw));
    __builtin_amdgcn_s_setprio(1);
#pragma unroll
    for (int mi = 0; mi < 4; ++mi)
#pragma unroll
      for (int ni = 0; ni < 4; ++ni)
        acc[mi][ni] = __builtin_amdgcn_mfma_f32_16x16x32_bf16(af[mi], bfr[ni], acc[mi][ni], 0, 0, 0);
    __builtin_amdgcn_s_setprio(0);
  }

  // ---- fused epilogue ----
  const int m_base = m0 + wm;
  if (by < 16) {
    const int   cbase = (by < 14) ? by * 256 : (by - 14) * 256;
    const float scale = (by < 14) ? QK_SCALE_L2E : 1.0f;
    const float* bias = (by < 14) ? q_b : k_b;
    u16*        obuf  = (by < 14) ? qbuf : kbuf;
    const int   ld    = (by < 14) ? HID : KVD;
#pragma unroll
    for (int ni = 0; ni < 2; ++ni) {
      const int cc0  = cbase + nbase[ni] + lr;   // within-head offset < 64
      const int head = cc0 >> 7;
      const int d    = cc0 & 63;
      const float blo = bias[cc0];
      const float bhi = bias[cc0 + 64];
#pragma unroll
      for (int mi = 0; mi < 4; ++mi) {
#pragma unroll
        for (int r = 0; r < 4; ++r) {
          const int m = m_base + mi * 16 + lg * 4 + r;
          const float lo = acc[mi][ni][r]     + blo;
          const float hi = acc[mi][ni + 2][r] + bhi;
          const float cs = cosb[m * HD + d];
          const float sn = sinb[m * HD + d];
          obuf[(size_t)m * ld + head * HD + d]      = nbf((lo * cs - hi * sn) * scale);
          obuf[(size_t)m * ld + head * HD + d + 64] = nbf((lo * sn + hi * cs) * scale);
        }
      }
    }
  } else {
    const int cbase = (by - 16) * 256;
#pragma unroll
    for (int ni = 0; ni < 4; ++ni) {
      const int vc = cbase + nbase[ni] + lr;
      const float bv = v_b[vc];
#pragma unroll
      for (int mi = 0; mi < 4; ++mi) {
#pragma unroll
        for (int r = 0; r < 4; ++r) {
          const int m = m_base + mi * 16 + lg * 4 + r;
          vbuf[(size_t)m * KVD + vc] = nbf(acc[mi][ni][r] + bv);
        }
      }
    }
  }
}

// O-proj: partials [2][S][HID]; grid (16, 14, 2); XCD swizzle (224=8*28)
__global__ __launch_bounds__(512) void oproj_gemm_kernel(
    const u16* __restrict__ ao, const u16* __restrict__ owb, u16* __restrict__ part)
{
  __shared__ u16 lds[3 * 12288];
  const int lin = blockIdx.y * 16 + blockIdx.x;   // 0..223
  const int swz = (lin & 7) * 28 + (lin >> 3);
  const int m0  = (swz & 15) * 128;
  const int n0  = (swz >> 4) * 256;
  const int k0  = blockIdx.z * KSPLIT_LEN;
  u16* Cz = part + (size_t)blockIdx.z * S_LEN * HID;
  gemm_core_128x256_bk32(lds, ao + (size_t)m0 * HID + k0,
                         owb + (size_t)n0 * HID + k0,
                         Cz + (size_t)m0 * HID + n0, HID, HID, KSPLIT_LEN / 32);
}

// ---------------- V transpose: [S][KVD] -> [KVD][S] ----------------
__global__ __launch_bounds__(256) void vtrans_kernel(
    const u16* __restrict__ v, u16* __restrict__ vt)
{
  __shared__ u16 tile[32][33];
  const int bs = blockIdx.x * 32;
  const int bd = blockIdx.y * 32;
  const int tx = threadIdx.x & 31;
  const int ty = threadIdx.x >> 5;
#pragma unroll
  for (int i = 0; i < 4; ++i) {
    const int r = ty * 4 + i;
    tile[r][tx] = v[(size_t)(bs + r) * KVD + bd + tx];
  }
  __syncthreads();
#pragma unroll
  for (int i = 0; i < 4; ++i) {
    const int r = ty * 4 + i;
    vt[(size_t)(bd + r) * S_LEN + bs + tx] = tile[tx][r];
  }
}

// ------- O-proj reduce: f32 out = p0 + p1 -------
__global__ __launch_bounds__(256) void o_reduce_kernel(
    const u16* __restrict__ part, float* __restrict__ out)
{
  const int i = blockIdx.x * 256 + threadIdx.x;   // 4 elems each
  const uint2 a = ((const uint2*)part)[i];
  const uint2 b = ((const uint2*)(part + (size_t)S_LEN * HID))[i];
  float4 o;
  o.x = bf2f((u16)(a.x & 0xffff)) + bf2f((u16)(b.x & 0xffff));
  o.y = bf2f((u16)(a.x >> 16))    + bf2f((u16)(b.x >> 16));
  o.z = bf2f((u16)(a.y & 0xffff)) + bf2f((u16)(b.y & 0xffff));
  o.w = bf2f((u16)(a.y >> 16))    + bf2f((u16)(b.y >> 16));
  ((float4*)out)[i] = o;
}

// ---------------- Flash attention (causal, GQA) ----------------
// R11 structure (proven best). Unchanged.
__global__ __launch_bounds__(256) void attn_kernel(
    const u16* __restrict__ qb, const u16* __restrict__ kb,
    const u16* __restrict__ vtb, u16* __restrict__ ao)
{
  __shared__ u16 Ks[2][64 * 128];   // [kv][d], swizzled
  __shared__ u16 Vts[2][128 * 64];  // [d][kv], swizzled
  __shared__ u16 Ps[4][16 * 64];    // per-wave P, swizzled

  const int h   = blockIdx.y;
  const int kvh = h / REP;
  const int lo  = blockIdx.x;       // 0..15
  const int hi  = 31 - lo;
  const int t   = threadIdx.x;
  const int w   = t >> 6;
  const int l   = t & 63;
  const int lr  = l & 15;
  const int lg  = l >> 4;
  const int sw  = (lr & 7) << 3;
  const f32x4 fz = {0.f, 0.f, 0.f, 0.f};
  short8 onesv;
#pragma unroll
  for (int i = 0; i < 8; ++i) onesv[i] = (short)0x3F80;  // bf16 1.0

  const u16* kbh  = kb + kvh * HD;
  const u16* vtbh = vtb + (size_t)kvh * HD * S_LEN;

  int tile = lo;
  short8 qf[4];
  {
    const u16* qrow = qb + (size_t)(tile * 64 + w * 16 + lr) * HID + h * HD;
#pragma unroll
    for (int dk = 0; dk < 4; ++dk)
      qf[dk] = *(const short8*)(qrow + dk * 32 + lg * 8);
  }

  float m_r[4];
  f32x4 lacc;       // row-sum accumulator via ones-MFMA
  f32x4 o_acc[8];
#pragma unroll
  for (int r = 0; r < 4; ++r) m_r[r] = -1e30f;
  lacc = fz;
#pragma unroll
  for (int db = 0; db < 8; ++db) o_acc[db] = fz;

  // ---- prologue: stage kv tile 0 into buf 0 ----
#pragma unroll
  for (int i = 0; i < 4; ++i) {
    const int e  = (i * 256 + t) * 8;
    const int rk = e >> 7;
    const int ck = (e & 127) ^ ((rk & 7) << 3);
    GLL16(kbh + (size_t)rk * KVD + ck, &Ks[0][0] + e);
    const int rv = e >> 6;
    const int cv = (e & 63) ^ ((rv & 7) << 3);
    GLL16(vtbh + (size_t)rv * S_LEN + cv, &Vts[0][0] + e);
  }
  __syncthreads();

#pragma unroll 1
  for (int j = 0; j < 33; ++j) {
    const int buf = j & 1;
    if (j + 1 < 33) {
      const int jn  = j + 1;
      const int kvn = ((jn <= lo) ? jn : (jn - lo - 1)) * 64;
#pragma unroll
      for (int i = 0; i < 4; ++i) {
        const int e  = (i * 256 + t) * 8;
        const int rk = e >> 7;
        const int ck = (e & 127) ^ ((rk & 7) << 3);
        GLL16(kbh + (size_t)(kvn + rk) * KVD + ck, &Ks[buf ^ 1][0] + e);
        const int rv = e >> 6;
        const int cv = (e & 63) ^ ((rv & 7) << 3);
        GLL16(vtbh + (size_t)rv * S_LEN + kvn + cv, &Vts[buf ^ 1][0] + e);
      }
    }

    const int kv0 = ((j <= lo) ? j : (j - lo - 1)) * 64;
    const u16* ks = &Ks[buf][0];
    const u16* vs = &Vts[buf][0];

    f32x4 sacc[4];
#pragma unroll
    for (int kvt = 0; kvt < 4; ++kvt) sacc[kvt] = fz;
    __builtin_amdgcn_s_setprio(1);
#pragma unroll
    for (int kvt = 0; kvt < 4; ++kvt) {
#pragma unroll
      for (int dk = 0; dk < 4; ++dk) {
        const short8 kf = *(const short8*)(ks + (kvt * 16 + lr) * 128 + ((dk * 32 + lg * 8) ^ sw));
        sacc[kvt] = __builtin_amdgcn_mfma_f32_16x16x32_bf16(qf[dk], kf, sacc[kvt], 0, 0, 0);
      }
    }
    __builtin_amdgcn_s_setprio(0);

    const bool last_of_half = (j == lo) || (j == 32);
    if (last_of_half) {
      const int q0w = tile * 64 + w * 16;
#pragma unroll
      for (int kvt = 0; kvt < 4; ++kvt) {
        const int col = kv0 + kvt * 16 + lr;
#pragma unroll
        for (int r = 0; r < 4; ++r) {
          if (col > q0w + lg * 4 + r) sacc[kvt][r] = -1e30f;
        }
      }
    }

    float lm[4];
    bool ok = true;
#pragma unroll
    for (int r = 0; r < 4; ++r) {
      lm[r] = fmaxf(fmaxf(sacc[0][r], sacc[1][r]), fmaxf(sacc[2][r], sacc[3][r]));
      ok = ok && (lm[r] <= m_r[r] + 8.f);
    }
    if (!__all(ok)) {
#pragma unroll
      for (int r = 0; r < 4; ++r) {
        float tm = lm[r];
        tm = fmaxf(tm, __shfl_xor(tm, 1));
        tm = fmaxf(tm, __shfl_xor(tm, 2));
        tm = fmaxf(tm, __shfl_xor(tm, 4));
        tm = fmaxf(tm, __shfl_xor(tm, 8));
        const float mn = fmaxf(m_r[r], tm);
        const float alpha = exp2f(m_r[r] - mn);
        m_r[r] = mn;
        lacc[r] *= alpha;
#pragma unroll
        for (int db = 0; db < 8; ++db) o_acc[db][r] *= alpha;
      }
    }

#pragma unroll
    for (int kvt = 0; kvt < 4; ++kvt) {
#pragma unroll
      for (int r = 0; r < 4; ++r) {
        const int prow = lg * 4 + r;
        Ps[w][prow * 64 + ((kvt * 16 + lr) ^ ((prow & 7) << 3))] =
            nbf(exp2f(sacc[kvt][r] - m_r[r]));
      }
    }

    short8 pf[2];
#pragma unroll
    for (int ks2 = 0; ks2 < 2; ++ks2)
      pf[ks2] = *(const short8*)(&Ps[w][0] + lr * 64 + ((ks2 * 32 + lg * 8) ^ sw));

    __builtin_amdgcn_s_setprio(1);
    lacc = __builtin_amdgcn_mfma_f32_16x16x32_bf16(pf[0], onesv, lacc, 0, 0, 0);
    lacc = __builtin_amdgcn_mfma_f32_16x16x32_bf16(pf[1], onesv, lacc, 0, 0, 0);
#pragma unroll
    for (int db = 0; db < 8; ++db) {
#pragma unroll
      for (int ks2 = 0; ks2 < 2; ++ks2) {
        const short8 vf = *(const short8*)(vs + (db * 16 + lr) * 64 + ((ks2 * 32 + lg * 8) ^ sw));
        o_acc[db] = __builtin_amdgcn_mfma_f32_16x16x32_bf16(pf[ks2], vf, o_acc[db], 0, 0, 0);
      }
    }
    __builtin_amdgcn_s_setprio(0);

    if (last_of_half) {
#pragma unroll
      for (int r = 0; r < 4; ++r) {
        const float inv = 1.0f / lacc[r];
        u16* orow = ao + (size_t)(tile * 64 + w * 16 + lg * 4 + r) * HID + h * HD;
#pragma unroll
        for (int db = 0; db < 8; ++db)
          orow[db * 16 + lr] = nbf(o_acc[db][r] * inv);
      }
      if (j != 32) {
        tile = hi;
        const u16* qrow = qb + (size_t)(tile * 64 + w * 16 + lr) * HID + h * HD;
#pragma unroll
        for (int dk = 0; dk < 4; ++dk)
          qf[dk] = *(const short8*)(qrow + dk * 32 + lg * 8);
#pragma unroll
        for (int r = 0; r < 4; ++r) m_r[r] = -1e30f;
        lacc = fz;
#pragma unroll
        for (int db = 0; db < 8; ++db) o_acc[db] = fz;
      }
    }
    __syncthreads();
  }
}

// ---------------- launch ----------------
extern "C" void kernel_launch(void* const* d_in, const int* in_sizes, int n_in,
                              void* d_out, int out_size, void* d_ws, size_t ws_size,
                              hipStream_t stream) {
  const float* hidden = (const float*)d_in[0];
  const float* cosb = (const float*)d_in[2];
  const float* sinb = (const float*)d_in[3];
  const float* q_w  = (const float*)d_in[4];
  const float* q_b  = (const float*)d_in[5];
  const float* k_w  = (const float*)d_in[6];
  const float* k_b  = (const float*)d_in[7];
  const float* v_w  = (const float*)d_in[8];
  const float* v_b  = (const float*)d_in[9];
  const float* o_w  = (const float*)d_in[10];
  float* out = (float*)d_out;

  char* p = (char*)d_ws;
  u16* hb   = (u16*)p; p += (size_t)S_LEN * HID * 2;
  u16* qwb  = (u16*)p; p += (size_t)HID * HID * 2;
  u16* kwb  = (u16*)p; p += (size_t)KVD * HID * 2;
  u16* vwb  = (u16*)p; p += (size_t)KVD * HID * 2;
  u16* owb  = (u16*)p; p += (size_t)HID * HID * 2;
  u16* qbuf = (u16*)p; p += (size_t)S_LEN * HID * 2;
  u16* kbuf = (u16*)p; p += (size_t)S_LEN * KVD * 2;
  u16* vbuf = (u16*)p; p += (size_t)S_LEN * KVD * 2;
  u16* vtb  = (u16*)p; p += (size_t)KVD * S_LEN * 2;
  u16* ao   = (u16*)p; p += (size_t)S_LEN * HID * 2;
  u16* part = (u16*)p; p += (size_t)2 * S_LEN * HID * 2;  // oproj partials
  if ((size_t)(p - (char*)d_ws) > ws_size) return;

  cvt_all_kernel<<<dim3(1024, 5), 256, 0, stream>>>(
      hidden, q_w, k_w, v_w, o_w, hb, qwb, kwb, vwb, owb);

  qkv_gemm_fused_kernel<<<dim3(16, 18), 512, 0, stream>>>(
      hb, qwb, kwb, vwb, q_b, k_b, v_b, cosb, sinb, qbuf, kbuf, vbuf);
  vtrans_kernel<<<dim3(S_LEN / 32, KVD / 32), 256, 0, stream>>>(vbuf, vtb);

  attn_kernel<<<dim3(16, 28), 256, 0, stream>>>(qbuf, kbuf, vtb, ao);

  oproj_gemm_kernel<<<dim3(16, 14, 2), 512, 0, stream>>>(ao, owb, part);
  o_reduce_kernel<<<(S_LEN * HID / 4) / 256, 256, 0, stream>>>(part, out);
}

// Round 17
// 281.613 us; speedup vs baseline: 1.0389x; 1.0020x over previous
//
#include <hip/hip_runtime.h>
#include <hip/hip_bf16.h>
#include <stdint.h>
#include <stddef.h>

#define S_LEN 2048
#define HID   3584
#define NH    28
#define NKV   4
#define HD    128
#define REP   7
#define KVD   512
#define NQKV  4608          // 3584 + 512 + 512
#define KSPLIT_LEN 1792     // 3584 / 2 (oproj)
// QK scale with log2(e) folded in: softmax uses exp2
#define QK_SCALE_L2E 0.12752462155f   // (1/sqrt(128)) * log2(e)

typedef unsigned short u16;
typedef short short8 __attribute__((ext_vector_type(8)));
typedef float f32x4 __attribute__((ext_vector_type(4)));

__device__ __forceinline__ u16 f2bf(float f) {
  union { float f; uint32_t u; } v; v.f = f;
  uint32_t r = v.u + 0x7fffu + ((v.u >> 16) & 1u);
  return (u16)(r >> 16);
}
__device__ __forceinline__ float bf2f(u16 u) {
  union { uint32_t u; float f; } v; v.u = ((uint32_t)u) << 16;
  return v.f;
}
__device__ __forceinline__ u16 nbf(float f) {  // native 1-op RNE cvt
  __hip_bfloat16 h = __float2bfloat16(f);
  return *reinterpret_cast<u16*>(&h);
}

#define GLL16(gp, lp) __builtin_amdgcn_global_load_lds( \
    (const __attribute__((address_space(1))) void*)(gp), \
    (__attribute__((address_space(3))) void*)(lp), 16, 0, 0)

// ---------------- f32 -> bf16 bulk convert (all 5 buffers, one launch) -------
__global__ __launch_bounds__(256) void cvt_all_kernel(
    const float* __restrict__ h, const float* __restrict__ qw,
    const float* __restrict__ kw, const float* __restrict__ vw,
    const float* __restrict__ ow,
    u16* __restrict__ hb, u16* __restrict__ qwb, u16* __restrict__ kwb,
    u16* __restrict__ vwb, u16* __restrict__ owb)
{
  const float* src; u16* dst; int n4;
  switch (blockIdx.y) {
    case 0: src = h;  dst = hb;  n4 = S_LEN * HID / 4; break;
    case 1: src = qw; dst = qwb; n4 = HID * HID / 4;   break;
    case 2: src = kw; dst = kwb; n4 = KVD * HID / 4;   break;
    case 3: src = vw; dst = vwb; n4 = KVD * HID / 4;   break;
    default: src = ow; dst = owb; n4 = HID * HID / 4;  break;
  }
  int i = blockIdx.x * blockDim.x + threadIdx.x;
  const int stride = gridDim.x * blockDim.x;
  for (; i < n4; i += stride) {
    float4 v = reinterpret_cast<const float4*>(src)[i];
    uint2 o;
    o.x = (uint32_t)f2bf(v.x) | ((uint32_t)f2bf(v.y) << 16);
    o.y = (uint32_t)f2bf(v.z) | ((uint32_t)f2bf(v.w) << 16);
    reinterpret_cast<uint2*>(dst)[i] = o;
  }
}

#define SWZC(e) ((e & 31) ^ ((((e >> 5) & 3) ^ ((e >> 7) & 3)) << 3))
#define STAGE3(kt, buf) do {                                          \
    { const int e_ = t * 8;                                           \
      const int r_ = e_ >> 5;  const int c_ = SWZC(e_);               \
      GLL16(A + (size_t)(kt) * 32 + (size_t)r_ * lda + c_, (buf) + e_); } \
    _Pragma("unroll")                                                 \
    for (int i_ = 0; i_ < 2; ++i_) {                                  \
      const int e_ = (i_ * 512 + t) * 8;                              \
      const int r_ = e_ >> 5;  const int c_ = SWZC(e_);               \
      GLL16(W + (size_t)(kt) * 32 + (size_t)r_ * lda + c_, (buf) + 4096 + e_); } \
  } while (0)

// ---- GEMM core (oproj): 128x256 tile, 8 waves, BK=32, triple-buffered LDS,
// counted vmcnt. Unchanged proven R11 core.
__device__ __forceinline__ void gemm_core_128x256_bk32(
    u16* lds, const u16* __restrict__ A, const u16* __restrict__ W,
    u16* __restrict__ C, int ldC, int lda, int T)
{
  const int t  = threadIdx.x;       // 0..511
  const int l  = t & 63;
  const int w  = t >> 6;            // 0..7
  const int lr = l & 15;
  const int lg = l >> 4;
  const int wm = (w >> 2) << 6;     // 0 or 64
  const int wn = (w & 3) << 6;      // 0,64,128,192
  const int sw = (((lr & 3) ^ ((lr >> 2) & 3)) << 3);

  const f32x4 fz = {0.f, 0.f, 0.f, 0.f};
  f32x4 acc[4][4];
#pragma unroll
  for (int i = 0; i < 4; ++i)
#pragma unroll
    for (int j = 0; j < 4; ++j) acc[i][j] = fz;

  STAGE3(0, lds);
  STAGE3(1, lds + 12288);

#pragma unroll 1
  for (int tk = 0; tk < T; ++tk) {
    if (tk + 1 < T) { asm volatile("s_waitcnt vmcnt(3)" ::: "memory"); }
    else            { asm volatile("s_waitcnt vmcnt(0)" ::: "memory"); }
    __builtin_amdgcn_sched_barrier(0);
    __builtin_amdgcn_s_barrier();
    __builtin_amdgcn_sched_barrier(0);

    if (tk + 2 < T) {
      u16* nb = lds + ((tk + 2) % 3) * 12288;
      STAGE3(tk + 2, nb);
    }

    const u16* As_ = lds + (tk % 3) * 12288;
    const u16* Bs_ = As_ + 4096;
    short8 af[4], bfr[4];
#pragma unroll
    for (int mi = 0; mi < 4; ++mi)
      af[mi] = *(const short8*)(As_ + (wm + mi * 16 + lr) * 32 + ((lg * 8) ^ sw));
#pragma unroll
    for (int ni = 0; ni < 4; ++ni)
      bfr[ni] = *(const short8*)(Bs_ + (wn + ni * 16 + lr) * 32 + ((lg * 8) ^ sw));
    __builtin_amdgcn_s_setprio(1);
#pragma unroll
    for (int mi = 0; mi < 4; ++mi)
#pragma unroll
      for (int ni = 0; ni < 4; ++ni)
        acc[mi][ni] = __builtin_amdgcn_mfma_f32_16x16x32_bf16(af[mi], bfr[ni], acc[mi][ni], 0, 0, 0);
    __builtin_amdgcn_s_setprio(0);
  }

#pragma unroll
  for (int ni = 0; ni < 4; ++ni) {
    const int n = wn + ni * 16 + lr;
#pragma unroll
    for (int mi = 0; mi < 4; ++mi) {
#pragma unroll
      for (int r = 0; r < 4; ++r) {
        const int m = wm + mi * 16 + lg * 4 + r;
        C[(size_t)m * ldC + n] = f2bf(acc[mi][ni][r]);
      }
    }
  }
}

// ---- QKV fused GEMM (z=1): same core loop, remapped B-fragments so that
// acc[mi][ni] / acc[mi][ni+2] form RoPE pairs (d, d+64) in the same lane.
// Epilogue: bias + RoPE(+scale) -> qbuf/kbuf; bias -> vbuf. No partials.
__global__ __launch_bounds__(512) void qkv_gemm_fused_kernel(
    const u16* __restrict__ hb,
    const u16* __restrict__ qwb, const u16* __restrict__ kwb, const u16* __restrict__ vwb,
    const float* __restrict__ q_b, const float* __restrict__ k_b,
    const float* __restrict__ v_b,
    const float* __restrict__ cosb, const float* __restrict__ sinb,
    u16* __restrict__ qbuf, u16* __restrict__ kbuf, u16* __restrict__ vbuf)
{
  __shared__ u16 lds[3 * 12288];
  const int lin = blockIdx.y * 16 + blockIdx.x;   // 0..287
  const int swz = (lin & 7) * 36 + (lin >> 3);    // bijective XCD chunking
  const int m0  = (swz & 15) * 128;
  const int by  = swz >> 4;                       // 0..17
  const int lda = HID;

  const u16* A = hb + (size_t)m0 * HID;
  const u16* W;
  if (by < 14)      W = qwb + (size_t)by * 256 * HID;
  else if (by < 16) W = kwb + (size_t)(by - 14) * 256 * HID;
  else              W = vwb + (size_t)(by - 16) * 256 * HID;

  const int t  = threadIdx.x;
  const int l  = t & 63;
  const int w  = t >> 6;
  const int lr = l & 15;
  const int lg = l >> 4;
  const int wm = (w >> 2) << 6;
  const int w4 = w & 3;
  const int sw = (((lr & 3) ^ ((lr >> 2) & 3)) << 3);

  int nbase[4];
#pragma unroll
  for (int ni = 0; ni < 4; ++ni)
    nbase[ni] = (w4 >> 1) * 128 + (w4 & 1) * 32 + (ni & 1) * 16 + (ni >> 1) * 64;

  const f32x4 fz = {0.f, 0.f, 0.f, 0.f};
  f32x4 acc[4][4];
#pragma unroll
  for (int i = 0; i < 4; ++i)
#pragma unroll
    for (int j = 0; j < 4; ++j) acc[i][j] = fz;

  STAGE3(0, lds);
  STAGE3(1, lds + 12288);

  const int T = HID / 32;   // 112
#pragma unroll 1
  for (int tk = 0; tk < T; ++tk) {
    if (tk + 1 < T) { asm volatile("s_waitcnt vmcnt(3)" ::: "memory"); }
    else            { asm volatile("s_waitcnt vmcnt(0)" ::: "memory"); }
    __builtin_amdgcn_sched_barrier(0);
    __builtin_amdgcn_s_barrier();
    __builtin_amdgcn_sched_barrier(0);

    if (tk + 2 < T) {
      u16* nb = lds + ((tk + 2) % 3) * 12288;
      STAGE3(tk + 2, nb);
    }

    const u16* As_ = lds + (tk % 3) * 12288;
    const u16* Bs_ = As_ + 4096;
    short8 af[4], bfr[4];
#pragma unroll
    for (int mi = 0; mi < 4; ++mi)
      af[mi] = *(const short8*)(As_ + (wm + mi * 16 + lr) * 32 + ((lg * 8) ^ sw));
#pragma unroll
    for (int ni = 0; ni < 4; ++ni)
      bfr[ni] = *(const short8*)(Bs_ + (nbase[ni] + lr) * 32 + ((lg * 8) ^ sw));
    __builtin_amdgcn_s_setprio(1);
#pragma unroll
    for (int mi = 0; mi < 4; ++mi)
#pragma unroll
      for (int ni = 0; ni < 4; ++ni)
        acc[mi][ni] = __builtin_amdgcn_mfma_f32_16x16x32_bf16(af[mi], bfr[ni], acc[mi][ni], 0, 0, 0);
    __builtin_amdgcn_s_setprio(0);
  }

  // ---- fused epilogue ----
  const int m_base = m0 + wm;
  if (by < 16) {
    const int   cbase = (by < 14) ? by * 256 : (by - 14) * 256;
    const float scale = (by < 14) ? QK_SCALE_L2E : 1.0f;
    const float* bias = (by < 14) ? q_b : k_b;
    u16*        obuf  = (by < 14) ? qbuf : kbuf;
    const int   ld    = (by < 14) ? HID : KVD;
#pragma unroll
    for (int ni = 0; ni < 2; ++ni) {
      const int cc0  = cbase + nbase[ni] + lr;   // within-head offset < 64
      const int head = cc0 >> 7;
      const int d    = cc0 & 63;
      const float blo = bias[cc0];
      const float bhi = bias[cc0 + 64];
#pragma unroll
      for (int mi = 0; mi < 4; ++mi) {
#pragma unroll
        for (int r = 0; r < 4; ++r) {
          const int m = m_base + mi * 16 + lg * 4 + r;
          const float lo = acc[mi][ni][r]     + blo;
          const float hi = acc[mi][ni + 2][r] + bhi;
          const float cs = cosb[m * HD + d];
          const float sn = sinb[m * HD + d];
          obuf[(size_t)m * ld + head * HD + d]      = nbf((lo * cs - hi * sn) * scale);
          obuf[(size_t)m * ld + head * HD + d + 64] = nbf((lo * sn + hi * cs) * scale);
        }
      }
    }
  } else {
    const int cbase = (by - 16) * 256;
#pragma unroll
    for (int ni = 0; ni < 4; ++ni) {
      const int vc = cbase + nbase[ni] + lr;
      const float bv = v_b[vc];
#pragma unroll
      for (int mi = 0; mi < 4; ++mi) {
#pragma unroll
        for (int r = 0; r < 4; ++r) {
          const int m = m_base + mi * 16 + lg * 4 + r;
          vbuf[(size_t)m * KVD + vc] = nbf(acc[mi][ni][r] + bv);
        }
      }
    }
  }
}

// O-proj: partials [2][S][HID]; grid (16, 14, 2); XCD swizzle (224=8*28)
__global__ __launch_bounds__(512) void oproj_gemm_kernel(
    const u16* __restrict__ ao, const u16* __restrict__ owb, u16* __restrict__ part)
{
  __shared__ u16 lds[3 * 12288];
  const int lin = blockIdx.y * 16 + blockIdx.x;   // 0..223
  const int swz = (lin & 7) * 28 + (lin >> 3);
  const int m0  = (swz & 15) * 128;
  const int n0  = (swz >> 4) * 256;
  const int k0  = blockIdx.z * KSPLIT_LEN;
  u16* Cz = part + (size_t)blockIdx.z * S_LEN * HID;
  gemm_core_128x256_bk32(lds, ao + (size_t)m0 * HID + k0,
                         owb + (size_t)n0 * HID + k0,
                         Cz + (size_t)m0 * HID + n0, HID, HID, KSPLIT_LEN / 32);
}

// ---------------- V transpose: [S][KVD] -> [KVD][S] ----------------
__global__ __launch_bounds__(256) void vtrans_kernel(
    const u16* __restrict__ v, u16* __restrict__ vt)
{
  __shared__ u16 tile[32][33];
  const int bs = blockIdx.x * 32;
  const int bd = blockIdx.y * 32;
  const int tx = threadIdx.x & 31;
  const int ty = threadIdx.x >> 5;
#pragma unroll
  for (int i = 0; i < 4; ++i) {
    const int r = ty * 4 + i;
    tile[r][tx] = v[(size_t)(bs + r) * KVD + bd + tx];
  }
  __syncthreads();
#pragma unroll
  for (int i = 0; i < 4; ++i) {
    const int r = ty * 4 + i;
    vt[(size_t)(bd + r) * S_LEN + bs + tx] = tile[tx][r];
  }
}

// ------- O-proj reduce: f32 out = p0 + p1 (uint4 loads, 8 elems/thread) ----
__global__ __launch_bounds__(256) void o_reduce_kernel(
    const u16* __restrict__ part, float* __restrict__ out)
{
  const int i = blockIdx.x * 256 + threadIdx.x;   // 8 elems each
  const uint4 a = ((const uint4*)part)[i];
  const uint4 b = ((const uint4*)(part + (size_t)S_LEN * HID))[i];
  float4 o0, o1;
  o0.x = bf2f((u16)(a.x & 0xffff)) + bf2f((u16)(b.x & 0xffff));
  o0.y = bf2f((u16)(a.x >> 16))    + bf2f((u16)(b.x >> 16));
  o0.z = bf2f((u16)(a.y & 0xffff)) + bf2f((u16)(b.y & 0xffff));
  o0.w = bf2f((u16)(a.y >> 16))    + bf2f((u16)(b.y >> 16));
  o1.x = bf2f((u16)(a.z & 0xffff)) + bf2f((u16)(b.z & 0xffff));
  o1.y = bf2f((u16)(a.z >> 16))    + bf2f((u16)(b.z >> 16));
  o1.z = bf2f((u16)(a.w & 0xffff)) + bf2f((u16)(b.w & 0xffff));
  o1.w = bf2f((u16)(a.w >> 16))    + bf2f((u16)(b.w >> 16));
  ((float4*)out)[2 * i]     = o0;
  ((float4*)out)[2 * i + 1] = o1;
}

// ---------------- Flash attention (causal, GQA) ----------------
// R11 structure (proven best) + XCD-aware block swizzle: each XCD gets a
// contiguous 56-block chunk (3.5 heads) so each kv-head's K/V (1MB) is
// served by at most 2 XCD L2s instead of all 8.
__global__ __launch_bounds__(256) void attn_kernel(
    const u16* __restrict__ qb, const u16* __restrict__ kb,
    const u16* __restrict__ vtb, u16* __restrict__ ao)
{
  __shared__ u16 Ks[2][64 * 128];   // [kv][d], swizzled
  __shared__ u16 Vts[2][128 * 64];  // [d][kv], swizzled
  __shared__ u16 Ps[4][16 * 64];    // per-wave P, swizzled

  const int lin = blockIdx.y * 16 + blockIdx.x;   // 0..447, dispatch-linear
  const int swb = (lin & 7) * 56 + (lin >> 3);    // bijective XCD chunking
  const int h   = swb >> 4;                       // 0..27
  const int lo  = swb & 15;                       // 0..15
  const int kvh = h / REP;
  const int hi  = 31 - lo;
  const int t   = threadIdx.x;
  const int w   = t >> 6;
  const int l   = t & 63;
  const int lr  = l & 15;
  const int lg  = l >> 4;
  const int sw  = (lr & 7) << 3;
  const f32x4 fz = {0.f, 0.f, 0.f, 0.f};
  short8 onesv;
#pragma unroll
  for (int i = 0; i < 8; ++i) onesv[i] = (short)0x3F80;  // bf16 1.0

  const u16* kbh  = kb + kvh * HD;
  const u16* vtbh = vtb + (size_t)kvh * HD * S_LEN;

  int tile = lo;
  short8 qf[4];
  {
    const u16* qrow = qb + (size_t)(tile * 64 + w * 16 + lr) * HID + h * HD;
#pragma unroll
    for (int dk = 0; dk < 4; ++dk)
      qf[dk] = *(const short8*)(qrow + dk * 32 + lg * 8);
  }

  float m_r[4];
  f32x4 lacc;       // row-sum accumulator via ones-MFMA
  f32x4 o_acc[8];
#pragma unroll
  for (int r = 0; r < 4; ++r) m_r[r] = -1e30f;
  lacc = fz;
#pragma unroll
  for (int db = 0; db < 8; ++db) o_acc[db] = fz;

  // ---- prologue: stage kv tile 0 into buf 0 ----
#pragma unroll
  for (int i = 0; i < 4; ++i) {
    const int e  = (i * 256 + t) * 8;
    const int rk = e >> 7;
    const int ck = (e & 127) ^ ((rk & 7) << 3);
    GLL16(kbh + (size_t)rk * KVD + ck, &Ks[0][0] + e);
    const int rv = e >> 6;
    const int cv = (e & 63) ^ ((rv & 7) << 3);
    GLL16(vtbh + (size_t)rv * S_LEN + cv, &Vts[0][0] + e);
  }
  __syncthreads();

#pragma unroll 1
  for (int j = 0; j < 33; ++j) {
    const int buf = j & 1;
    if (j + 1 < 33) {
      const int jn  = j + 1;
      const int kvn = ((jn <= lo) ? jn : (jn - lo - 1)) * 64;
#pragma unroll
      for (int i = 0; i < 4; ++i) {
        const int e  = (i * 256 + t) * 8;
        const int rk = e >> 7;
        const int ck = (e & 127) ^ ((rk & 7) << 3);
        GLL16(kbh + (size_t)(kvn + rk) * KVD + ck, &Ks[buf ^ 1][0] + e);
        const int rv = e >> 6;
        const int cv = (e & 63) ^ ((rv & 7) << 3);
        GLL16(vtbh + (size_t)rv * S_LEN + kvn + cv, &Vts[buf ^ 1][0] + e);
      }
    }

    const int kv0 = ((j <= lo) ? j : (j - lo - 1)) * 64;
    const u16* ks = &Ks[buf][0];
    const u16* vs = &Vts[buf][0];

    f32x4 sacc[4];
#pragma unroll
    for (int kvt = 0; kvt < 4; ++kvt) sacc[kvt] = fz;
    __builtin_amdgcn_s_setprio(1);
#pragma unroll
    for (int kvt = 0; kvt < 4; ++kvt) {
#pragma unroll
      for (int dk = 0; dk < 4; ++dk) {
        const short8 kf = *(const short8*)(ks + (kvt * 16 + lr) * 128 + ((dk * 32 + lg * 8) ^ sw));
        sacc[kvt] = __builtin_amdgcn_mfma_f32_16x16x32_bf16(qf[dk], kf, sacc[kvt], 0, 0, 0);
      }
    }
    __builtin_amdgcn_s_setprio(0);

    const bool last_of_half = (j == lo) || (j == 32);
    if (last_of_half) {
      const int q0w = tile * 64 + w * 16;
#pragma unroll
      for (int kvt = 0; kvt < 4; ++kvt) {
        const int col = kv0 + kvt * 16 + lr;
#pragma unroll
        for (int r = 0; r < 4; ++r) {
          if (col > q0w + lg * 4 + r) sacc[kvt][r] = -1e30f;
        }
      }
    }

    float lm[4];
    bool ok = true;
#pragma unroll
    for (int r = 0; r < 4; ++r) {
      lm[r] = fmaxf(fmaxf(sacc[0][r], sacc[1][r]), fmaxf(sacc[2][r], sacc[3][r]));
      ok = ok && (lm[r] <= m_r[r] + 8.f);
    }
    if (!__all(ok)) {
#pragma unroll
      for (int r = 0; r < 4; ++r) {
        float tm = lm[r];
        tm = fmaxf(tm, __shfl_xor(tm, 1));
        tm = fmaxf(tm, __shfl_xor(tm, 2));
        tm = fmaxf(tm, __shfl_xor(tm, 4));
        tm = fmaxf(tm, __shfl_xor(tm, 8));
        const float mn = fmaxf(m_r[r], tm);
        const float alpha = exp2f(m_r[r] - mn);
        m_r[r] = mn;
        lacc[r] *= alpha;
#pragma unroll
        for (int db = 0; db < 8; ++db) o_acc[db][r] *= alpha;
      }
    }

#pragma unroll
    for (int kvt = 0; kvt < 4; ++kvt) {
#pragma unroll
      for (int r = 0; r < 4; ++r) {
        const int prow = lg * 4 + r;
        Ps[w][prow * 64 + ((kvt * 16 + lr) ^ ((prow & 7) << 3))] =
            nbf(exp2f(sacc[kvt][r] - m_r[r]));
      }
    }

    short8 pf[2];
#pragma unroll
    for (int ks2 = 0; ks2 < 2; ++ks2)
      pf[ks2] = *(const short8*)(&Ps[w][0] + lr * 64 + ((ks2 * 32 + lg * 8) ^ sw));

    __builtin_amdgcn_s_setprio(1);
    lacc = __builtin_amdgcn_mfma_f32_16x16x32_bf16(pf[0], onesv, lacc, 0, 0, 0);
    lacc = __builtin_amdgcn_mfma_f32_16x16x32_bf16(pf[1], onesv, lacc, 0, 0, 0);
#pragma unroll
    for (int db = 0; db < 8; ++db) {
#pragma unroll
      for (int ks2 = 0; ks2 < 2; ++ks2) {
        const short8 vf = *(const short8*)(vs + (db * 16 + lr) * 64 + ((ks2 * 32 + lg * 8) ^ sw));
        o_acc[db] = __builtin_amdgcn_mfma_f32_16x16x32_bf16(pf[ks2], vf, o_acc[db], 0, 0, 0);
      }
    }
    __builtin_amdgcn_s_setprio(0);

    if (last_of_half) {
#pragma unroll
      for (int r = 0; r < 4; ++r) {
        const float inv = 1.0f / lacc[r];
        u16* orow = ao + (size_t)(tile * 64 + w * 16 + lg * 4 + r) * HID + h * HD;
#pragma unroll
        for (int db = 0; db < 8; ++db)
          orow[db * 16 + lr] = nbf(o_acc[db][r] * inv);
      }
      if (j != 32) {
        tile = hi;
        const u16* qrow = qb + (size_t)(tile * 64 + w * 16 + lr) * HID + h * HD;
#pragma unroll
        for (int dk = 0; dk < 4; ++dk)
          qf[dk] = *(const short8*)(qrow + dk * 32 + lg * 8);
#pragma unroll
        for (int r = 0; r < 4; ++r) m_r[r] = -1e30f;
        lacc = fz;
#pragma unroll
        for (int db = 0; db < 8; ++db) o_acc[db] = fz;
      }
    }
    __syncthreads();
  }
}

// ---------------- launch ----------------
extern "C" void kernel_launch(void* const* d_in, const int* in_sizes, int n_in,
                              void* d_out, int out_size, void* d_ws, size_t ws_size,
                              hipStream_t stream) {
  const float* hidden = (const float*)d_in[0];
  const float* cosb = (const float*)d_in[2];
  const float* sinb = (const float*)d_in[3];
  const float* q_w  = (const float*)d_in[4];
  const float* q_b  = (const float*)d_in[5];
  const float* k_w  = (const float*)d_in[6];
  const float* k_b  = (const float*)d_in[7];
  const float* v_w  = (const float*)d_in[8];
  const float* v_b  = (const float*)d_in[9];
  const float* o_w  = (const float*)d_in[10];
  float* out = (float*)d_out;

  char* p = (char*)d_ws;
  u16* hb   = (u16*)p; p += (size_t)S_LEN * HID * 2;
  u16* qwb  = (u16*)p; p += (size_t)HID * HID * 2;
  u16* kwb  = (u16*)p; p += (size_t)KVD * HID * 2;
  u16* vwb  = (u16*)p; p += (size_t)KVD * HID * 2;
  u16* owb  = (u16*)p; p += (size_t)HID * HID * 2;
  u16* qbuf = (u16*)p; p += (size_t)S_LEN * HID * 2;
  u16* kbuf = (u16*)p; p += (size_t)S_LEN * KVD * 2;
  u16* vbuf = (u16*)p; p += (size_t)S_LEN * KVD * 2;
  u16* vtb  = (u16*)p; p += (size_t)KVD * S_LEN * 2;
  u16* ao   = (u16*)p; p += (size_t)S_LEN * HID * 2;
  u16* part = (u16*)p; p += (size_t)2 * S_LEN * HID * 2;  // oproj partials
  if ((size_t)(p - (char*)d_ws) > ws_size) return;

  cvt_all_kernel<<<dim3(1024, 5), 256, 0, stream>>>(
      hidden, q_w, k_w, v_w, o_w, hb, qwb, kwb, vwb, owb);

  qkv_gemm_fused_kernel<<<dim3(16, 18), 512, 0, stream>>>(
      hb, qwb, kwb, vwb, q_b, k_b, v_b, cosb, sinb, qbuf, kbuf, vbuf);
  vtrans_kernel<<<dim3(S_LEN / 32, KVD / 32), 256, 0, stream>>>(vbuf, vtb);

  attn_kernel<<<dim3(16, 28), 256, 0, stream>>>(qbuf, kbuf, vtb, ao);

  oproj_gemm_kernel<<<dim3(16, 14, 2), 512, 0, stream>>>(ao, owb, part);
  o_reduce_kernel<<<(S_LEN * HID / 8) / 256, 256, 0, stream>>>(part, out);
}

// Round 18
// 276.684 us; speedup vs baseline: 1.0574x; 1.0178x over previous
//
#include <hip/hip_runtime.h>
#include <hip/hip_bf16.h>
#include <stdint.h>
#include <stddef.h>

#define S_LEN 2048
#define HID   3584
#define NH    28
#define NKV   4
#define HD    128
#define REP   7
#define KVD   512
#define NQKV  4608          // 3584 + 512 + 512
#define KSPLIT_LEN 1792     // 3584 / 2 (oproj)
// QK scale with log2(e) folded in: softmax uses exp2
#define QK_SCALE_L2E 0.12752462155f   // (1/sqrt(128)) * log2(e)

typedef unsigned short u16;
typedef short short8 __attribute__((ext_vector_type(8)));
typedef float f32x4 __attribute__((ext_vector_type(4)));

__device__ __forceinline__ u16 f2bf(float f) {
  union { float f; uint32_t u; } v; v.f = f;
  uint32_t r = v.u + 0x7fffu + ((v.u >> 16) & 1u);
  return (u16)(r >> 16);
}
__device__ __forceinline__ float bf2f(u16 u) {
  union { uint32_t u; float f; } v; v.u = ((uint32_t)u) << 16;
  return v.f;
}
__device__ __forceinline__ u16 nbf(float f) {  // native 1-op RNE cvt
  __hip_bfloat16 h = __float2bfloat16(f);
  return *reinterpret_cast<u16*>(&h);
}

#define GLL16(gp, lp) __builtin_amdgcn_global_load_lds( \
    (const __attribute__((address_space(1))) void*)(gp), \
    (__attribute__((address_space(3))) void*)(lp), 16, 0, 0)

// ---------------- f32 -> bf16 bulk convert (all 5 buffers, one launch) -------
__global__ __launch_bounds__(256) void cvt_all_kernel(
    const float* __restrict__ h, const float* __restrict__ qw,
    const float* __restrict__ kw, const float* __restrict__ vw,
    const float* __restrict__ ow,
    u16* __restrict__ hb, u16* __restrict__ qwb, u16* __restrict__ kwb,
    u16* __restrict__ vwb, u16* __restrict__ owb)
{
  const float* src; u16* dst; int n4;
  switch (blockIdx.y) {
    case 0: src = h;  dst = hb;  n4 = S_LEN * HID / 4; break;
    case 1: src = qw; dst = qwb; n4 = HID * HID / 4;   break;
    case 2: src = kw; dst = kwb; n4 = KVD * HID / 4;   break;
    case 3: src = vw; dst = vwb; n4 = KVD * HID / 4;   break;
    default: src = ow; dst = owb; n4 = HID * HID / 4;  break;
  }
  int i = blockIdx.x * blockDim.x + threadIdx.x;
  const int stride = gridDim.x * blockDim.x;
  for (; i < n4; i += stride) {
    float4 v = reinterpret_cast<const float4*>(src)[i];
    uint2 o;
    o.x = (uint32_t)f2bf(v.x) | ((uint32_t)f2bf(v.y) << 16);
    o.y = (uint32_t)f2bf(v.z) | ((uint32_t)f2bf(v.w) << 16);
    reinterpret_cast<uint2*>(dst)[i] = o;
  }
}

#define SWZC(e) ((e & 31) ^ ((((e >> 5) & 3) ^ ((e >> 7) & 3)) << 3))
#define STAGE3(kt, buf) do {                                          \
    { const int e_ = t * 8;                                           \
      const int r_ = e_ >> 5;  const int c_ = SWZC(e_);               \
      GLL16(A + (size_t)(kt) * 32 + (size_t)r_ * lda + c_, (buf) + e_); } \
    _Pragma("unroll")                                                 \
    for (int i_ = 0; i_ < 2; ++i_) {                                  \
      const int e_ = (i_ * 512 + t) * 8;                              \
      const int r_ = e_ >> 5;  const int c_ = SWZC(e_);               \
      GLL16(W + (size_t)(kt) * 32 + (size_t)r_ * lda + c_, (buf) + 4096 + e_); } \
  } while (0)

// ---- GEMM core (oproj): 128x256 tile, 8 waves, BK=32, triple-buffered LDS,
// counted vmcnt. Unchanged proven R11 core.
__device__ __forceinline__ void gemm_core_128x256_bk32(
    u16* lds, const u16* __restrict__ A, const u16* __restrict__ W,
    u16* __restrict__ C, int ldC, int lda, int T)
{
  const int t  = threadIdx.x;       // 0..511
  const int l  = t & 63;
  const int w  = t >> 6;            // 0..7
  const int lr = l & 15;
  const int lg = l >> 4;
  const int wm = (w >> 2) << 6;     // 0 or 64
  const int wn = (w & 3) << 6;      // 0,64,128,192
  const int sw = (((lr & 3) ^ ((lr >> 2) & 3)) << 3);

  const f32x4 fz = {0.f, 0.f, 0.f, 0.f};
  f32x4 acc[4][4];
#pragma unroll
  for (int i = 0; i < 4; ++i)
#pragma unroll
    for (int j = 0; j < 4; ++j) acc[i][j] = fz;

  STAGE3(0, lds);
  STAGE3(1, lds + 12288);

#pragma unroll 1
  for (int tk = 0; tk < T; ++tk) {
    if (tk + 1 < T) { asm volatile("s_waitcnt vmcnt(3)" ::: "memory"); }
    else            { asm volatile("s_waitcnt vmcnt(0)" ::: "memory"); }
    __builtin_amdgcn_sched_barrier(0);
    __builtin_amdgcn_s_barrier();
    __builtin_amdgcn_sched_barrier(0);

    if (tk + 2 < T) {
      u16* nb = lds + ((tk + 2) % 3) * 12288;
      STAGE3(tk + 2, nb);
    }

    const u16* As_ = lds + (tk % 3) * 12288;
    const u16* Bs_ = As_ + 4096;
    short8 af[4], bfr[4];
#pragma unroll
    for (int mi = 0; mi < 4; ++mi)
      af[mi] = *(const short8*)(As_ + (wm + mi * 16 + lr) * 32 + ((lg * 8) ^ sw));
#pragma unroll
    for (int ni = 0; ni < 4; ++ni)
      bfr[ni] = *(const short8*)(Bs_ + (wn + ni * 16 + lr) * 32 + ((lg * 8) ^ sw));
    __builtin_amdgcn_s_setprio(1);
#pragma unroll
    for (int mi = 0; mi < 4; ++mi)
#pragma unroll
      for (int ni = 0; ni < 4; ++ni)
        acc[mi][ni] = __builtin_amdgcn_mfma_f32_16x16x32_bf16(af[mi], bfr[ni], acc[mi][ni], 0, 0, 0);
    __builtin_amdgcn_s_setprio(0);
  }

#pragma unroll
  for (int ni = 0; ni < 4; ++ni) {
    const int n = wn + ni * 16 + lr;
#pragma unroll
    for (int mi = 0; mi < 4; ++mi) {
#pragma unroll
      for (int r = 0; r < 4; ++r) {
        const int m = wm + mi * 16 + lg * 4 + r;
        C[(size_t)m * ldC + n] = f2bf(acc[mi][ni][r]);
      }
    }
  }
}

// ---- QKV GEMM, 128x192 tiles (z=1, work-balanced): grid (16,24)=384 blocks,
// LDS 3x20KB=60KB -> 2 blocks/CU, one dispatch round, doubled CUs carry
// 224x20KB=4.5MB staging (vs 5.4MB at 256-wide). Weights read as one
// contiguous [4608][3584] block (qwb/kwb/vwb adjacent in ws). Raw bf16 out;
// bias+RoPE+V-transpose in qkv_reduce<1>.
#define KEY192(r) ((((r) & 3) ^ (((r) >> 2) & 3)) << 3)
__global__ __launch_bounds__(512) void qkv_gemm192_kernel(
    const u16* __restrict__ hb, const u16* __restrict__ wall,
    u16* __restrict__ raw)
{
  __shared__ u16 lds[3 * 10240];
  const int lin = blockIdx.y * 16 + blockIdx.x;   // 0..383
  const int swz = (lin & 7) * 48 + (lin >> 3);    // bijective XCD chunking
  const int m0  = (swz & 15) * 128;
  const int pan = swz >> 4;                       // 0..23

  const u16* A = hb + (size_t)m0 * HID;
  const u16* W = wall + (size_t)pan * 192 * HID;

  const int t  = threadIdx.x;
  const int l  = t & 63;
  const int w  = t >> 6;
  const int lr = l & 15;
  const int lg = l >> 4;
  const int wm = (w >> 2) << 6;     // 0 or 64
  const int wn = (w & 3) * 48;      // 0,48,96,144
  const int sw = KEY192(lr);

#define STG192(kt, buf) do {                                            \
    { const int e_ = t * 8; const int r_ = e_ >> 5;                     \
      const int c_ = (e_ & 31) ^ KEY192(r_);                            \
      GLL16(A + (size_t)(kt) * 32 + (size_t)r_ * HID + c_, (buf) + e_); \
      GLL16(W + (size_t)(kt) * 32 + (size_t)r_ * HID + c_, (buf) + 4096 + e_); } \
    if (w < 4) {                                                        \
      const int e_ = 4096 + t * 8; const int r_ = e_ >> 5;              \
      const int c_ = (e_ & 31) ^ KEY192(r_);                            \
      GLL16(W + (size_t)(kt) * 32 + (size_t)r_ * HID + c_, (buf) + 4096 + e_); } \
  } while (0)

  const f32x4 fz = {0.f, 0.f, 0.f, 0.f};
  f32x4 acc[4][3];
#pragma unroll
  for (int i = 0; i < 4; ++i)
#pragma unroll
    for (int j = 0; j < 3; ++j) acc[i][j] = fz;

  STG192(0, lds);
  STG192(1, lds + 10240);

  const int T = HID / 32;   // 112
#pragma unroll 1
  for (int tk = 0; tk < T; ++tk) {
    if (tk + 1 < T) {
      if (w < 4) { asm volatile("s_waitcnt vmcnt(3)" ::: "memory"); }
      else       { asm volatile("s_waitcnt vmcnt(2)" ::: "memory"); }
    } else       { asm volatile("s_waitcnt vmcnt(0)" ::: "memory"); }
    __builtin_amdgcn_sched_barrier(0);
    __builtin_amdgcn_s_barrier();
    __builtin_amdgcn_sched_barrier(0);

    if (tk + 2 < T) {
      u16* nb = lds + ((tk + 2) % 3) * 10240;
      STG192(tk + 2, nb);
    }

    const u16* As_ = lds + (tk % 3) * 10240;
    const u16* Bs_ = As_ + 4096;
    short8 af[4], bfr[3];
#pragma unroll
    for (int mi = 0; mi < 4; ++mi)
      af[mi] = *(const short8*)(As_ + (wm + mi * 16 + lr) * 32 + ((lg * 8) ^ sw));
#pragma unroll
    for (int ni = 0; ni < 3; ++ni)
      bfr[ni] = *(const short8*)(Bs_ + (wn + ni * 16 + lr) * 32 + ((lg * 8) ^ sw));
    __builtin_amdgcn_s_setprio(1);
#pragma unroll
    for (int mi = 0; mi < 4; ++mi)
#pragma unroll
      for (int ni = 0; ni < 3; ++ni)
        acc[mi][ni] = __builtin_amdgcn_mfma_f32_16x16x32_bf16(af[mi], bfr[ni], acc[mi][ni], 0, 0, 0);
    __builtin_amdgcn_s_setprio(0);
  }
#undef STG192

#pragma unroll
  for (int ni = 0; ni < 3; ++ni) {
    const int n = pan * 192 + wn + ni * 16 + lr;
#pragma unroll
    for (int mi = 0; mi < 4; ++mi) {
#pragma unroll
      for (int r = 0; r < 4; ++r) {
        const int m = m0 + wm + mi * 16 + lg * 4 + r;
        raw[(size_t)m * NQKV + n] = f2bf(acc[mi][ni][r]);
      }
    }
  }
}

// ------- QKV reduce (Z=1): bias + RoPE(+scale) + V-transpose -------
template<int Z>
__global__ __launch_bounds__(256) void qkv_reduce_kernel(
    const u16* __restrict__ part,
    const float* __restrict__ q_b, const float* __restrict__ k_b,
    const float* __restrict__ v_b,
    const float* __restrict__ cosb, const float* __restrict__ sinb,
    u16* __restrict__ qbuf, u16* __restrict__ kbuf, u16* __restrict__ vtb)
{
  const int s   = blockIdx.y;
  const int c   = blockIdx.x * 256 + threadIdx.x;   // 0..2303
  const int seg = c >> 6;
  const int d   = c & 63;
  const u16* pr = part + (size_t)s * NQKV;

  int base, bb;
  const float* bias;
  if (seg < 28)      { base = seg * 128;              bb = base; bias = q_b; }
  else if (seg < 32) { base = HID + (seg - 28) * 128; bb = (seg - 28) * 128; bias = k_b; }
  else               { base = HID + KVD + (seg - 32) * 128; bb = (seg - 32) * 128; bias = v_b; }

  float lo = bias[bb + d];
  float hi = bias[bb + d + 64];
#pragma unroll
  for (int z = 0; z < Z; ++z) {
    lo += bf2f(pr[(size_t)z * S_LEN * NQKV + base + d]);
    hi += bf2f(pr[(size_t)z * S_LEN * NQKV + base + d + 64]);
  }

  if (seg < 28) {
    const float cc = cosb[s * HD + d];
    const float ss = sinb[s * HD + d];
    qbuf[(size_t)s * HID + bb + d]      = f2bf((lo * cc - hi * ss) * QK_SCALE_L2E);
    qbuf[(size_t)s * HID + bb + d + 64] = f2bf((lo * ss + hi * cc) * QK_SCALE_L2E);
  } else if (seg < 32) {
    const float cc = cosb[s * HD + d];
    const float ss = sinb[s * HD + d];
    kbuf[(size_t)s * KVD + bb + d]      = f2bf(lo * cc - hi * ss);
    kbuf[(size_t)s * KVD + bb + d + 64] = f2bf(lo * ss + hi * cc);
  } else {
    vtb[(size_t)(bb + d) * S_LEN + s]      = f2bf(lo);
    vtb[(size_t)(bb + d + 64) * S_LEN + s] = f2bf(hi);
  }
}

// O-proj: partials [2][S][HID]; grid (16, 14, 2); XCD swizzle (224=8*28)
__global__ __launch_bounds__(512) void oproj_gemm_kernel(
    const u16* __restrict__ ao, const u16* __restrict__ owb, u16* __restrict__ part)
{
  __shared__ u16 lds[3 * 12288];
  const int lin = blockIdx.y * 16 + blockIdx.x;   // 0..223
  const int swz = (lin & 7) * 28 + (lin >> 3);
  const int m0  = (swz & 15) * 128;
  const int n0  = (swz >> 4) * 256;
  const int k0  = blockIdx.z * KSPLIT_LEN;
  u16* Cz = part + (size_t)blockIdx.z * S_LEN * HID;
  gemm_core_128x256_bk32(lds, ao + (size_t)m0 * HID + k0,
                         owb + (size_t)n0 * HID + k0,
                         Cz + (size_t)m0 * HID + n0, HID, HID, KSPLIT_LEN / 32);
}

// ------- O-proj reduce: f32 out = p0 + p1 (uint4 loads, 8 elems/thread) ----
__global__ __launch_bounds__(256) void o_reduce_kernel(
    const u16* __restrict__ part, float* __restrict__ out)
{
  const int i = blockIdx.x * 256 + threadIdx.x;   // 8 elems each
  const uint4 a = ((const uint4*)part)[i];
  const uint4 b = ((const uint4*)(part + (size_t)S_LEN * HID))[i];
  float4 o0, o1;
  o0.x = bf2f((u16)(a.x & 0xffff)) + bf2f((u16)(b.x & 0xffff));
  o0.y = bf2f((u16)(a.x >> 16))    + bf2f((u16)(b.x >> 16));
  o0.z = bf2f((u16)(a.y & 0xffff)) + bf2f((u16)(b.y & 0xffff));
  o0.w = bf2f((u16)(a.y >> 16))    + bf2f((u16)(b.y >> 16));
  o1.x = bf2f((u16)(a.z & 0xffff)) + bf2f((u16)(b.z & 0xffff));
  o1.y = bf2f((u16)(a.z >> 16))    + bf2f((u16)(b.z >> 16));
  o1.z = bf2f((u16)(a.w & 0xffff)) + bf2f((u16)(b.w & 0xffff));
  o1.w = bf2f((u16)(a.w >> 16))    + bf2f((u16)(b.w >> 16));
  ((float4*)out)[2 * i]     = o0;
  ((float4*)out)[2 * i + 1] = o1;
}

// ---------------- Flash attention (causal, GQA) ----------------
// R16 version: R11 structure + XCD-aware block swizzle.
__global__ __launch_bounds__(256) void attn_kernel(
    const u16* __restrict__ qb, const u16* __restrict__ kb,
    const u16* __restrict__ vtb, u16* __restrict__ ao)
{
  __shared__ u16 Ks[2][64 * 128];   // [kv][d], swizzled
  __shared__ u16 Vts[2][128 * 64];  // [d][kv], swizzled
  __shared__ u16 Ps[4][16 * 64];    // per-wave P, swizzled

  const int lin = blockIdx.y * 16 + blockIdx.x;   // 0..447, dispatch-linear
  const int swb = (lin & 7) * 56 + (lin >> 3);    // bijective XCD chunking
  const int h   = swb >> 4;                       // 0..27
  const int lo  = swb & 15;                       // 0..15
  const int kvh = h / REP;
  const int hi  = 31 - lo;
  const int t   = threadIdx.x;
  const int w   = t >> 6;
  const int l   = t & 63;
  const int lr  = l & 15;
  const int lg  = l >> 4;
  const int sw  = (lr & 7) << 3;
  const f32x4 fz = {0.f, 0.f, 0.f, 0.f};
  short8 onesv;
#pragma unroll
  for (int i = 0; i < 8; ++i) onesv[i] = (short)0x3F80;  // bf16 1.0

  const u16* kbh  = kb + kvh * HD;
  const u16* vtbh = vtb + (size_t)kvh * HD * S_LEN;

  int tile = lo;
  short8 qf[4];
  {
    const u16* qrow = qb + (size_t)(tile * 64 + w * 16 + lr) * HID + h * HD;
#pragma unroll
    for (int dk = 0; dk < 4; ++dk)
      qf[dk] = *(const short8*)(qrow + dk * 32 + lg * 8);
  }

  float m_r[4];
  f32x4 lacc;       // row-sum accumulator via ones-MFMA
  f32x4 o_acc[8];
#pragma unroll
  for (int r = 0; r < 4; ++r) m_r[r] = -1e30f;
  lacc = fz;
#pragma unroll
  for (int db = 0; db < 8; ++db) o_acc[db] = fz;

  // ---- prologue: stage kv tile 0 into buf 0 ----
#pragma unroll
  for (int i = 0; i < 4; ++i) {
    const int e  = (i * 256 + t) * 8;
    const int rk = e >> 7;
    const int ck = (e & 127) ^ ((rk & 7) << 3);
    GLL16(kbh + (size_t)rk * KVD + ck, &Ks[0][0] + e);
    const int rv = e >> 6;
    const int cv = (e & 63) ^ ((rv & 7) << 3);
    GLL16(vtbh + (size_t)rv * S_LEN + cv, &Vts[0][0] + e);
  }
  __syncthreads();

#pragma unroll 1
  for (int j = 0; j < 33; ++j) {
    const int buf = j & 1;
    if (j + 1 < 33) {
      const int jn  = j + 1;
      const int kvn = ((jn <= lo) ? jn : (jn - lo - 1)) * 64;
#pragma unroll
      for (int i = 0; i < 4; ++i) {
        const int e  = (i * 256 + t) * 8;
        const int rk = e >> 7;
        const int ck = (e & 127) ^ ((rk & 7) << 3);
        GLL16(kbh + (size_t)(kvn + rk) * KVD + ck, &Ks[buf ^ 1][0] + e);
        const int rv = e >> 6;
        const int cv = (e & 63) ^ ((rv & 7) << 3);
        GLL16(vtbh + (size_t)rv * S_LEN + kvn + cv, &Vts[buf ^ 1][0] + e);
      }
    }

    const int kv0 = ((j <= lo) ? j : (j - lo - 1)) * 64;
    const u16* ks = &Ks[buf][0];
    const u16* vs = &Vts[buf][0];

    f32x4 sacc[4];
#pragma unroll
    for (int kvt = 0; kvt < 4; ++kvt) sacc[kvt] = fz;
    __builtin_amdgcn_s_setprio(1);
#pragma unroll
    for (int kvt = 0; kvt < 4; ++kvt) {
#pragma unroll
      for (int dk = 0; dk < 4; ++dk) {
        const short8 kf = *(const short8*)(ks + (kvt * 16 + lr) * 128 + ((dk * 32 + lg * 8) ^ sw));
        sacc[kvt] = __builtin_amdgcn_mfma_f32_16x16x32_bf16(qf[dk], kf, sacc[kvt], 0, 0, 0);
      }
    }
    __builtin_amdgcn_s_setprio(0);

    const bool last_of_half = (j == lo) || (j == 32);
    if (last_of_half) {
      const int q0w = tile * 64 + w * 16;
#pragma unroll
      for (int kvt = 0; kvt < 4; ++kvt) {
        const int col = kv0 + kvt * 16 + lr;
#pragma unroll
        for (int r = 0; r < 4; ++r) {
          if (col > q0w + lg * 4 + r) sacc[kvt][r] = -1e30f;
        }
      }
    }

    float lm[4];
    bool ok = true;
#pragma unroll
    for (int r = 0; r < 4; ++r) {
      lm[r] = fmaxf(fmaxf(sacc[0][r], sacc[1][r]), fmaxf(sacc[2][r], sacc[3][r]));
      ok = ok && (lm[r] <= m_r[r] + 8.f);
    }
    if (!__all(ok)) {
#pragma unroll
      for (int r = 0; r < 4; ++r) {
        float tm = lm[r];
        tm = fmaxf(tm, __shfl_xor(tm, 1));
        tm = fmaxf(tm, __shfl_xor(tm, 2));
        tm = fmaxf(tm, __shfl_xor(tm, 4));
        tm = fmaxf(tm, __shfl_xor(tm, 8));
        const float mn = fmaxf(m_r[r], tm);
        const float alpha = exp2f(m_r[r] - mn);
        m_r[r] = mn;
        lacc[r] *= alpha;
#pragma unroll
        for (int db = 0; db < 8; ++db) o_acc[db][r] *= alpha;
      }
    }

#pragma unroll
    for (int kvt = 0; kvt < 4; ++kvt) {
#pragma unroll
      for (int r = 0; r < 4; ++r) {
        const int prow = lg * 4 + r;
        Ps[w][prow * 64 + ((kvt * 16 + lr) ^ ((prow & 7) << 3))] =
            nbf(exp2f(sacc[kvt][r] - m_r[r]));
      }
    }

    short8 pf[2];
#pragma unroll
    for (int ks2 = 0; ks2 < 2; ++ks2)
      pf[ks2] = *(const short8*)(&Ps[w][0] + lr * 64 + ((ks2 * 32 + lg * 8) ^ sw));

    __builtin_amdgcn_s_setprio(1);
    lacc = __builtin_amdgcn_mfma_f32_16x16x32_bf16(pf[0], onesv, lacc, 0, 0, 0);
    lacc = __builtin_amdgcn_mfma_f32_16x16x32_bf16(pf[1], onesv, lacc, 0, 0, 0);
#pragma unroll
    for (int db = 0; db < 8; ++db) {
#pragma unroll
      for (int ks2 = 0; ks2 < 2; ++ks2) {
        const short8 vf = *(const short8*)(vs + (db * 16 + lr) * 64 + ((ks2 * 32 + lg * 8) ^ sw));
        o_acc[db] = __builtin_amdgcn_mfma_f32_16x16x32_bf16(pf[ks2], vf, o_acc[db], 0, 0, 0);
      }
    }
    __builtin_amdgcn_s_setprio(0);

    if (last_of_half) {
#pragma unroll
      for (int r = 0; r < 4; ++r) {
        const float inv = 1.0f / lacc[r];
        u16* orow = ao + (size_t)(tile * 64 + w * 16 + lg * 4 + r) * HID + h * HD;
#pragma unroll
        for (int db = 0; db < 8; ++db)
          orow[db * 16 + lr] = nbf(o_acc[db][r] * inv);
      }
      if (j != 32) {
        tile = hi;
        const u16* qrow = qb + (size_t)(tile * 64 + w * 16 + lr) * HID + h * HD;
#pragma unroll
        for (int dk = 0; dk < 4; ++dk)
          qf[dk] = *(const short8*)(qrow + dk * 32 + lg * 8);
#pragma unroll
        for (int r = 0; r < 4; ++r) m_r[r] = -1e30f;
        lacc = fz;
#pragma unroll
        for (int db = 0; db < 8; ++db) o_acc[db] = fz;
      }
    }
    __syncthreads();
  }
}

// ---------------- launch ----------------
extern "C" void kernel_launch(void* const* d_in, const int* in_sizes, int n_in,
                              void* d_out, int out_size, void* d_ws, size_t ws_size,
                              hipStream_t stream) {
  const float* hidden = (const float*)d_in[0];
  const float* cosb = (const float*)d_in[2];
  const float* sinb = (const float*)d_in[3];
  const float* q_w  = (const float*)d_in[4];
  const float* q_b  = (const float*)d_in[5];
  const float* k_w  = (const float*)d_in[6];
  const float* k_b  = (const float*)d_in[7];
  const float* v_w  = (const float*)d_in[8];
  const float* v_b  = (const float*)d_in[9];
  const float* o_w  = (const float*)d_in[10];
  float* out = (float*)d_out;

  char* p = (char*)d_ws;
  u16* hb   = (u16*)p; p += (size_t)S_LEN * HID * 2;
  u16* qwb  = (u16*)p; p += (size_t)HID * HID * 2;   // qwb/kwb/vwb contiguous:
  u16* kwb  = (u16*)p; p += (size_t)KVD * HID * 2;   //  [4608][3584] weight block
  u16* vwb  = (u16*)p; p += (size_t)KVD * HID * 2;
  u16* owb  = (u16*)p; p += (size_t)HID * HID * 2;
  u16* qbuf = (u16*)p; p += (size_t)S_LEN * HID * 2;
  u16* kbuf = (u16*)p; p += (size_t)S_LEN * KVD * 2;
  u16* vtb  = (u16*)p; p += (size_t)KVD * S_LEN * 2;
  u16* ao   = (u16*)p; p += (size_t)S_LEN * HID * 2;
  u16* raw  = (u16*)p; p += (size_t)S_LEN * NQKV * 2;   // qkv raw out
  u16* part = (u16*)p; p += (size_t)2 * S_LEN * HID * 2; // oproj partials
  if ((size_t)(p - (char*)d_ws) > ws_size) return;

  cvt_all_kernel<<<dim3(1024, 5), 256, 0, stream>>>(
      hidden, q_w, k_w, v_w, o_w, hb, qwb, kwb, vwb, owb);

  qkv_gemm192_kernel<<<dim3(16, 24), 512, 0, stream>>>(hb, qwb, raw);
  qkv_reduce_kernel<1><<<dim3(9, S_LEN), 256, 0, stream>>>(
      raw, q_b, k_b, v_b, cosb, sinb, qbuf, kbuf, vtb);

  attn_kernel<<<dim3(16, 28), 256, 0, stream>>>(qbuf, kbuf, vtb, ao);

  oproj_gemm_kernel<<<dim3(16, 14, 2), 512, 0, stream>>>(ao, owb, part);
  o_reduce_kernel<<<(S_LEN * HID / 8) / 256, 256, 0, stream>>>(part, out);
}